// Round 1
// baseline (1574.847 us; speedup 1.0000x reference)
//
#include <hip/hip_runtime.h>
#include <hip/hip_bf16.h>

#define BATCH 16
#define CC    64
#define NN    4096
#define MIDD  8
#define KB    64   // key tile

// ---------------- projection: q = Wq x, k = Wk x, v = Wv x ------------------
// x:  [B][C][N]  (N = H*W contiguous)
// q,k stored [B][MID][N];  v stored [B][C][N]
__global__ __launch_bounds__(256) void proj_kernel(
    const float* __restrict__ x,
    const float* __restrict__ Wq,
    const float* __restrict__ Wk,
    const float* __restrict__ Wv,
    float* __restrict__ q,
    float* __restrict__ k,
    float* __restrict__ v)
{
    __shared__ float sWq[MIDD * CC];
    __shared__ float sWk[MIDD * CC];
    __shared__ float sWv[CC * CC];

    for (int i = threadIdx.x; i < MIDD * CC; i += 256) {
        sWq[i] = Wq[i];
        sWk[i] = Wk[i];
    }
    for (int i = threadIdx.x; i < CC * CC; i += 256) {
        sWv[i] = Wv[i];
    }
    __syncthreads();

    int g = blockIdx.x * 256 + threadIdx.x;   // 0 .. B*N-1
    int b = g >> 12;                          // / N
    int n = g & (NN - 1);

    // load one x column (coalesced across threads: consecutive n)
    float xc[CC];
#pragma unroll
    for (int c = 0; c < CC; ++c)
        xc[c] = x[((b * CC) + c) * NN + n];

#pragma unroll
    for (int m = 0; m < MIDD; ++m) {
        float aq = 0.f, ak = 0.f;
#pragma unroll
        for (int c = 0; c < CC; ++c) {
            aq += sWq[m * CC + c] * xc[c];
            ak += sWk[m * CC + c] * xc[c];
        }
        q[((b * MIDD) + m) * NN + n] = aq;
        k[((b * MIDD) + m) * NN + n] = ak;
    }

    for (int o = 0; o < CC; ++o) {
        float a = 0.f;
#pragma unroll
        for (int c = 0; c < CC; ++c)
            a += sWv[o * CC + c] * xc[c];
        v[((b * CC) + o) * NN + n] = a;
    }
}

// ---------------- fused flash attention + gamma*out + x ---------------------
// one thread = one query row j; O[64] accumulator in registers.
__global__ __launch_bounds__(256) void attn_kernel(
    const float* __restrict__ q,
    const float* __restrict__ k,
    const float* __restrict__ v,
    const float* __restrict__ x,
    const float* __restrict__ gamma,
    float* __restrict__ out)
{
    int b  = blockIdx.x >> 4;          // 16 query-tiles per batch
    int jt = blockIdx.x & 15;
    int j  = jt * 256 + threadIdx.x;   // query index

    __shared__ float Kt[MIDD][KB];     // K tile  [mid][key]
    __shared__ float Vt[KB][68];       // V tile transposed [key][o], pad 68 (16B-aligned rows)

    const float scale = 0.35355339059327373f;   // 1/sqrt(8)

    float qv[MIDD];
#pragma unroll
    for (int m = 0; m < MIDD; ++m)
        qv[m] = q[((b * MIDD) + m) * NN + j] * scale;

    float mrun = -1e30f;
    float lrun = 0.f;
    float O[CC];
#pragma unroll
    for (int o = 0; o < CC; ++o) O[o] = 0.f;

    for (int t0 = 0; t0 < NN; t0 += KB) {
        // stage K tile: 8*64 = 512 floats, 2 per thread
#pragma unroll
        for (int i = 0; i < 2; ++i) {
            int idx = threadIdx.x + i * 256;
            int m  = idx >> 6;
            int tt = idx & 63;
            Kt[m][tt] = k[((b * MIDD) + m) * NN + t0 + tt];
        }
        // stage V tile transposed: 64*64 = 4096 floats, 16 per thread
#pragma unroll
        for (int i = 0; i < 16; ++i) {
            int idx = threadIdx.x + i * 256;
            int o  = idx >> 6;
            int tt = idx & 63;
            Vt[tt][o] = v[((b * CC) + o) * NN + t0 + tt];
        }
        __syncthreads();

        for (int kk = 0; kk < KB; ++kk) {
            float s = 0.f;
#pragma unroll
            for (int m = 0; m < MIDD; ++m)
                s += qv[m] * Kt[m][kk];

            if (s > mrun) {            // rare (≈8 times over 4096 keys)
                float corr = __expf(mrun - s);
                mrun = s;
                lrun *= corr;
#pragma unroll
                for (int o = 0; o < CC; ++o) O[o] *= corr;
            }
            float p = __expf(s - mrun);
            lrun += p;

            const float4* vr = (const float4*)(&Vt[kk][0]);
#pragma unroll
            for (int o4 = 0; o4 < 16; ++o4) {
                float4 vv = vr[o4];
                O[o4 * 4 + 0] += p * vv.x;
                O[o4 * 4 + 1] += p * vv.y;
                O[o4 * 4 + 2] += p * vv.z;
                O[o4 * 4 + 3] += p * vv.w;
            }
        }
        __syncthreads();
    }

    float inv = 1.0f / lrun;
    float g   = gamma[0];
#pragma unroll
    for (int o = 0; o < CC; ++o) {
        int idx = ((b * CC) + o) * NN + j;
        out[idx] = g * (O[o] * inv) + x[idx];
    }
}

extern "C" void kernel_launch(void* const* d_in, const int* in_sizes, int n_in,
                              void* d_out, int out_size, void* d_ws, size_t ws_size,
                              hipStream_t stream) {
    const float* x     = (const float*)d_in[0];
    const float* Wq    = (const float*)d_in[1];
    const float* Wk    = (const float*)d_in[2];
    const float* Wv    = (const float*)d_in[3];
    const float* gamma = (const float*)d_in[4];
    float* out = (float*)d_out;

    // workspace layout (floats): q [B*MID*N] | k [B*MID*N] | v [B*C*N]
    float* q = (float*)d_ws;
    float* k = q + (size_t)BATCH * MIDD * NN;
    float* v = k + (size_t)BATCH * MIDD * NN;

    dim3 blk(256);
    dim3 grid_proj((BATCH * NN) / 256);     // 256 blocks
    proj_kernel<<<grid_proj, blk, 0, stream>>>(x, Wq, Wk, Wv, q, k, v);

    dim3 grid_attn(BATCH * (NN / 256));     // 256 blocks
    attn_kernel<<<grid_attn, blk, 0, stream>>>(q, k, v, x, gamma, out);
}

// Round 3
// 309.906 us; speedup vs baseline: 5.0817x; 5.0817x over previous
//
#include <hip/hip_runtime.h>
#include <hip/hip_bf16.h>

#define BATCH 16
#define CC    64
#define NN    4096
#define MIDD  8
#define KT    64   // keys staged per iteration

typedef __attribute__((ext_vector_type(8))) short short8;
typedef __attribute__((ext_vector_type(4))) float f32x4;

static __device__ __forceinline__ short f2bf_s(float f) {
    // round-to-nearest-even f32 -> bf16 (inputs are finite, non-NaN)
    unsigned u = __builtin_bit_cast(unsigned, f);
    u += 0x7FFFu + ((u >> 16) & 1u);
    return (short)(u >> 16);
}

// ---------------- projection: q = Wq x, k = Wk x, v = Wv x ------------------
// x: [B][C][N];  q,k: [B][MID][N] fp32;  v: [B][C][N] bf16
__global__ __launch_bounds__(256) void proj_kernel(
    const float* __restrict__ x,
    const float* __restrict__ Wq,
    const float* __restrict__ Wk,
    const float* __restrict__ Wv,
    float*  __restrict__ q,
    float*  __restrict__ k,
    ushort* __restrict__ v)
{
    __shared__ float sWq[MIDD * CC];
    __shared__ float sWk[MIDD * CC];
    __shared__ float sWv[CC * CC];

    for (int i = threadIdx.x; i < MIDD * CC; i += 256) {
        sWq[i] = Wq[i];
        sWk[i] = Wk[i];
    }
    for (int i = threadIdx.x; i < CC * CC; i += 256)
        sWv[i] = Wv[i];
    __syncthreads();

    int g = blockIdx.x * 256 + threadIdx.x;   // 0 .. B*N-1
    int b = g >> 12;
    int n = g & (NN - 1);

    float xc[CC];
#pragma unroll
    for (int c = 0; c < CC; ++c)
        xc[c] = x[((b * CC) + c) * NN + n];

#pragma unroll
    for (int m = 0; m < MIDD; ++m) {
        float aq = 0.f, ak = 0.f;
#pragma unroll
        for (int c = 0; c < CC; ++c) {
            aq += sWq[m * CC + c] * xc[c];
            ak += sWk[m * CC + c] * xc[c];
        }
        q[((b * MIDD) + m) * NN + n] = aq;
        k[((b * MIDD) + m) * NN + n] = ak;
    }

    for (int o = 0; o < CC; ++o) {
        float a = 0.f;
#pragma unroll
        for (int c = 0; c < CC; ++c)
            a += sWv[o * CC + c] * xc[c];
        v[((b * CC) + o) * NN + n] = (ushort)f2bf_s(a);
    }
}

// ---------------- fused flash attention (MFMA PV) + gamma*out + x -----------
// 4 waves/block; wave w owns queries [jt*64 + w*16, +16).
// Lane l: q = l&15, key-group g = l>>4 (keys 8g..8g+7 of each 32-key chunk).
// P computed directly in mfma B-frag layout; V^T as A-frag from swizzled LDS.
__global__ __launch_bounds__(256, 4) void attn_kernel(
    const float*  __restrict__ q,
    const float*  __restrict__ k,
    const ushort* __restrict__ v,     // bf16
    const float*  __restrict__ x,
    const float*  __restrict__ gamma,
    float* __restrict__ out)
{
    // bijective XCD swizzle: 1024 blocks, 128 contiguous tiles per XCD
    int bid = blockIdx.x;
    int wg  = (bid & 7) * 128 + (bid >> 3);
    int b   = wg >> 6;           // batch
    int jt  = wg & 63;           // q-tile within batch (64 queries)

    __shared__ float Kt[MIDD][KT];                 // 2 KB
    __shared__ __align__(16) char Vt[CC * 128];    // 8 KB, [o][k] bf16, 16B-slot XOR swizzle

    int tid  = threadIdx.x;
    int lane = tid & 63;
    int wv   = tid >> 6;
    int g    = lane >> 4;
    int qi   = lane & 15;
    int qrow = jt * 64 + wv * 16 + qi;

    // fold 1/sqrt(mid) and log2(e) so exp is a single v_exp_f32
    const float SCL = 0.35355339059327373f * 1.4426950408889634f;
    float qv[MIDD];
#pragma unroll
    for (int m = 0; m < MIDD; ++m)
        qv[m] = q[((b * MIDD) + m) * NN + qrow] * SCL;

    f32x4 acc[4];
#pragma unroll
    for (int f = 0; f < 4; ++f) {
        acc[f][0] = 0.f; acc[f][1] = 0.f; acc[f][2] = 0.f; acc[f][3] = 0.f;
    }
    float mrun = -1e30f, lsum = 0.f;

    const ushort* vbase = v + (size_t)b * CC * NN;
    const float*  kbase = k + (size_t)b * MIDD * NN;

    for (int t0 = 0; t0 < NN; t0 += KT) {
        __syncthreads();   // protect LDS from previous iteration's readers
        // ---- stage K tile: 8 x 64 fp32, 2 floats/thread
        {
            int m  = tid >> 5;
            int kk = (tid & 31) * 2;
            *(float2*)&Kt[m][kk] = *(const float2*)(kbase + m * NN + t0 + kk);
        }
        // ---- stage V tile: 64 x 64 bf16, 32 B/thread, XOR-swizzled 16B slots
        {
            int o  = tid >> 2;
            int k0 = (tid & 3) * 16;
            const uint4* src = (const uint4*)(vbase + o * NN + t0 + k0);
            uint4 a0 = src[0];
            uint4 a1 = src[1];
            int s0 = (tid & 3) * 2;
            char* row = Vt + o * 128;
            *(uint4*)(row + (((s0    ) ^ (o & 7)) << 4)) = a0;
            *(uint4*)(row + (((s0 + 1) ^ (o & 7)) << 4)) = a1;
        }
        __syncthreads();

#pragma unroll
        for (int c = 0; c < 2; ++c) {          // two 32-key chunks
            // ---- S = qK for this lane's 8 keys (broadcast K reads per group)
            float s[8];
#pragma unroll
            for (int j = 0; j < 8; ++j) s[j] = 0.f;
#pragma unroll
            for (int m = 0; m < MIDD; ++m) {
                const float4* kp = (const float4*)&Kt[m][c * 32 + g * 8];
                float4 ka = kp[0], kb = kp[1];
                s[0] += qv[m] * ka.x; s[1] += qv[m] * ka.y;
                s[2] += qv[m] * ka.z; s[3] += qv[m] * ka.w;
                s[4] += qv[m] * kb.x; s[5] += qv[m] * kb.y;
                s[6] += qv[m] * kb.z; s[7] += qv[m] * kb.w;
            }
            // ---- online softmax (log2 domain)
            float pmax = fmaxf(fmaxf(fmaxf(s[0], s[1]), fmaxf(s[2], s[3])),
                               fmaxf(fmaxf(s[4], s[5]), fmaxf(s[6], s[7])));
            pmax = fmaxf(pmax, __shfl_xor(pmax, 16));
            pmax = fmaxf(pmax, __shfl_xor(pmax, 32));
            if (pmax > mrun) {
                float corr = __builtin_amdgcn_exp2f(mrun - pmax);
                mrun = pmax;
                lsum *= corr;
#pragma unroll
                for (int f = 0; f < 4; ++f) {
                    acc[f][0] *= corr; acc[f][1] *= corr;
                    acc[f][2] *= corr; acc[f][3] *= corr;
                }
            }
            float p[8];
#pragma unroll
            for (int j = 0; j < 8; ++j)
                p[j] = __builtin_amdgcn_exp2f(s[j] - mrun);
            lsum += ((p[0] + p[1]) + (p[2] + p[3])) + ((p[4] + p[5]) + (p[6] + p[7]));

            short8 pb;
#pragma unroll
            for (int j = 0; j < 8; ++j) pb[j] = f2bf_s(p[j]);

            // ---- PV: D[o][q] += V^T[o][k] * P[k][q], 4 o-chunks of 16
            int slot = g + 4 * c;
#pragma unroll
            for (int f = 0; f < 4; ++f) {
                int o = f * 16 + qi;
                short8 va = *(const short8*)(Vt + o * 128 + ((slot ^ (o & 7)) << 4));
                acc[f] = __builtin_amdgcn_mfma_f32_16x16x32_bf16(va, pb, acc[f], 0, 0, 0);
            }
        }
    }

    // combine partial denominators across the 4 key-groups (same q)
    lsum += __shfl_xor(lsum, 16);
    lsum += __shfl_xor(lsum, 32);
    float inv = 1.0f / lsum;
    float gm  = gamma[0];

#pragma unroll
    for (int f = 0; f < 4; ++f) {
#pragma unroll
        for (int r = 0; r < 4; ++r) {
            int o = f * 16 + g * 4 + r;      // D row = (lane>>4)*4 + reg
            size_t idx = ((size_t)(b * CC + o)) * NN + jt * 64 + wv * 16 + qi;
            out[idx] = gm * acc[f][r] * inv + x[idx];
        }
    }
}

extern "C" void kernel_launch(void* const* d_in, const int* in_sizes, int n_in,
                              void* d_out, int out_size, void* d_ws, size_t ws_size,
                              hipStream_t stream) {
    const float* x     = (const float*)d_in[0];
    const float* Wq    = (const float*)d_in[1];
    const float* Wk    = (const float*)d_in[2];
    const float* Wv    = (const float*)d_in[3];
    const float* gamma = (const float*)d_in[4];
    float* out = (float*)d_out;

    // ws layout: q [B*MID*N] f32 | k [B*MID*N] f32 | v [B*C*N] bf16
    float*  q = (float*)d_ws;
    float*  k = q + (size_t)BATCH * MIDD * NN;
    ushort* v = (ushort*)(k + (size_t)BATCH * MIDD * NN);

    dim3 blk(256);
    proj_kernel<<<dim3((BATCH * NN) / 256), blk, 0, stream>>>(x, Wq, Wk, Wv, q, k, v);
    attn_kernel<<<dim3(BATCH * (NN / 64)), blk, 0, stream>>>(q, k, v, x, gamma, out);
}

// Round 4
// 302.074 us; speedup vs baseline: 5.2135x; 1.0259x over previous
//
#include <hip/hip_runtime.h>
#include <hip/hip_bf16.h>

#define BATCH 16
#define CC    64
#define NN    4096
#define MIDD  8

typedef __attribute__((ext_vector_type(8)))  short short8;
typedef __attribute__((ext_vector_type(16))) float f32x16;
typedef __attribute__((ext_vector_type(2)))  int   v2i;

static __device__ __forceinline__ ushort f2bf(float f) {
    return __bfloat16_as_ushort(__float2bfloat16(f));   // RNE
}

static __device__ __forceinline__ void glds16(const void* g, void* l) {
    __builtin_amdgcn_global_load_lds(
        (const __attribute__((address_space(1))) unsigned int*)g,
        (__attribute__((address_space(3))) unsigned int*)l, 16, 0, 0);
}

// dot of one weight row (LDS, broadcast reads) with xc[64] in registers
#define DOT(W, row, res) {                                                  \
    const float4* wp_ = (const float4*)((W) + (size_t)(row) * 64);          \
    float r0_ = 0.f, r1_ = 0.f;                                             \
    _Pragma("unroll")                                                       \
    for (int c4_ = 0; c4_ < 16; ++c4_) {                                    \
        float4 w4_ = wp_[c4_];                                              \
        r0_ += w4_.x * xc[c4_*4+0] + w4_.y * xc[c4_*4+1];                   \
        r1_ += w4_.z * xc[c4_*4+2] + w4_.w * xc[c4_*4+3];                   \
    }                                                                       \
    (res) = r0_ + r1_;                                                      \
}

// ---------------- projection ------------------------------------------------
// x:[B][C][N] f32 -> q:[B][8][N] f32 (unscaled), ktr:[B][N][16] bf16 (m 8..15 = 0),
// v:[B][C][N] bf16.  1024 blocks x 256 thr; wave = 64 consecutive columns.
__global__ __launch_bounds__(256, 4) void proj_kernel(
    const float* __restrict__ x,
    const float* __restrict__ Wq,
    const float* __restrict__ Wk,
    const float* __restrict__ Wv,
    float*  __restrict__ q,
    ushort* __restrict__ ktr,
    ushort* __restrict__ v)
{
    __shared__ float sWq[MIDD * CC];
    __shared__ float sWk[MIDD * CC];
    __shared__ float sWv[CC * CC];

    for (int i = threadIdx.x; i < MIDD * CC; i += 256) { sWq[i] = Wq[i]; sWk[i] = Wk[i]; }
    for (int i = threadIdx.x; i < CC * CC; i += 256) sWv[i] = Wv[i];
    __syncthreads();

    int tid = threadIdx.x;
    int wv  = tid >> 6;
    int nl  = tid & 63;
    int g   = blockIdx.x * 64 + nl;
    int b   = g >> 12;
    int n   = g & (NN - 1);

    const float* xp = x + (size_t)b * CC * NN + n;
    float xc[CC];
#pragma unroll
    for (int c = 0; c < CC; ++c) xc[c] = xp[(size_t)c * NN];

    if (wv == 0) {
        // q (8, f32), k^T (8 bf16 + 8 zero), v channels 0..3
#pragma unroll
        for (int m = 0; m < 8; ++m) {
            float a; DOT(sWq, m, a);
            q[((size_t)b * MIDD + m) * NN + n] = a;
        }
        union { uint4 u4[2]; ushort us[16]; } kb;
#pragma unroll
        for (int m = 0; m < 8; ++m) { float a; DOT(sWk, m, a); kb.us[m] = f2bf(a); }
#pragma unroll
        for (int m = 8; m < 16; ++m) kb.us[m] = 0;
        ushort* kd = ktr + ((size_t)b * NN + n) * 16;
        *(uint4*)(kd)     = kb.u4[0];
        *(uint4*)(kd + 8) = kb.u4[1];
#pragma unroll
        for (int i = 0; i < 4; ++i) {
            float a; DOT(sWv, i, a);
            v[((size_t)b * CC + i) * NN + n] = f2bf(a);
        }
    } else {
        int ch0 = wv * 20 - 16;   // 4 / 24 / 44
#pragma unroll
        for (int i = 0; i < 20; ++i) {
            float a; DOT(sWv, ch0 + i, a);
            v[((size_t)b * CC + ch0 + i) * NN + n] = f2bf(a);
        }
    }
}

// ---------------- fused flash attention (all-MFMA) + gamma*out + x ----------
// 512 blocks x 4 waves; wave owns 32 queries. 32-key chunks, 32x32x16 MFMA.
// No max-subtraction (|s| <= ~1.5 provably); lsum reduced once at the end.
__global__ __launch_bounds__(256, 2) void attn_kernel(
    const float*  __restrict__ qw,
    const ushort* __restrict__ ktr,
    const ushort* __restrict__ v,
    const float*  __restrict__ x,
    const float*  __restrict__ gamma,
    float* __restrict__ out)
{
    __shared__ __align__(16) char vt[8192];   // 2 x 4KB V-tile double buffer

    int bid = blockIdx.x;
    int wg  = (bid & 7) * 64 + (bid >> 3);    // bijective XCD swizzle (512 % 8 == 0)
    int b   = wg >> 5;
    int qt  = wg & 31;

    int tid  = threadIdx.x;
    int wv   = tid >> 6;
    int lane = tid & 63;
    int hi   = lane >> 5;
    int ql   = lane & 31;
    int q0   = qt * 128 + wv * 32;

    // fold 1/sqrt(8) * log2(e) into Q so exp is raw v_exp_f32
    const float SCL = 0.35355339059327373f * 1.4426950408889634f;

    // ---- Q B-frag (one-time): lanes hi=0 carry Q[m=0..7][q], hi=1 zeros
    const float* qp = qw + (size_t)b * MIDD * NN + q0 + ql;
    union { short8 s8; ushort us[8]; } qfu;
#pragma unroll
    for (int m = 0; m < 8; ++m) {
        float qv = qp[(size_t)m * NN] * SCL;
        qfu.us[m] = hi ? (ushort)0 : f2bf(qv);
    }
    short8 qf = qfu.s8;

    const ushort* kb_ = ktr + (size_t)b * NN * 16;
    const ushort* vb_ = v   + (size_t)b * CC * NN;

    // stage decode: thread t -> V-frag slot (kh, hi, ob, o5), linear LDS dest
    int skh = tid >> 7, shi = (tid >> 6) & 1, sob = (tid >> 5) & 1, so5 = tid & 31;
    const ushort* vsrc0 = vb_ + (size_t)(sob * 32 + so5) * NN + skh * 16 + shi * 8;
    int koff = ql * 16 + hi * 8;    // ka lane offset (ushorts)
    int loff = hi * 1024 + ql * 16; // va lane offset (bytes)

    f32x16 zf   = {};
    f32x16 acc0 = {};
    f32x16 acc1 = {};
    float  lsum = 0.f;
    float  gm   = gamma[0];

    // prologue: stage chunk 0, load K(0)
    glds16(vsrc0, vt + tid * 16);
    short8 kcur = *(const short8*)(kb_ + koff);

    for (int t = 0; t < 128; ++t) {
        int kbn = ((t + 1) & 127) * 32;                 // wraps to 0 on last iter (discarded)
        char* nbuf = vt + (((t + 1) & 1) << 12);
        const char* cbuf = vt + ((t & 1) << 12);

        __builtin_amdgcn_sched_barrier(0);
        __builtin_amdgcn_s_barrier();                   // everyone done reading nbuf
        glds16(vsrc0 + kbn, nbuf + tid * 16);           // prefetch V(t+1)
        short8 knext = *(const short8*)(kb_ + (size_t)kbn * 16 + koff);  // K(t+1)
        asm volatile("s_waitcnt vmcnt(2)" ::: "memory"); // V(t),K(t) landed; 2 newest in flight
        __builtin_amdgcn_s_barrier();                   // all waves' V(t) visible
        __builtin_amdgcn_sched_barrier(0);

        // S^T[key][q] for 32 keys x 32 queries (mid padded to 16)
        f32x16 s = __builtin_amdgcn_mfma_f32_32x32x16_bf16(kcur, qf, zf, 0, 0, 0);

        float p[16];
#pragma unroll
        for (int r = 0; r < 16; ++r) p[r] = __builtin_amdgcn_exp2f(s[r]);
        float t0 = (p[0] + p[1]) + (p[2] + p[3]);
        float t1 = (p[4] + p[5]) + (p[6] + p[7]);
        float t2 = (p[8] + p[9]) + (p[10] + p[11]);
        float t3 = (p[12] + p[13]) + (p[14] + p[15]);
        lsum += (t0 + t1) + (t2 + t3);

        unsigned u[8];
#pragma unroll
        for (int i = 0; i < 8; ++i)
            u[i] = (unsigned)f2bf(p[2*i]) | ((unsigned)f2bf(p[2*i+1]) << 16);

        // redistribute to PV B-frag layout: one swap fills two fragment words
        v2i r02 = __builtin_amdgcn_permlane32_swap(u[0], u[2], false, false);
        v2i r13 = __builtin_amdgcn_permlane32_swap(u[1], u[3], false, false);
        v2i r46 = __builtin_amdgcn_permlane32_swap(u[4], u[6], false, false);
        v2i r57 = __builtin_amdgcn_permlane32_swap(u[5], u[7], false, false);
        union { short8 s8; int i4[4]; } P0, P1;
        P0.i4[0] = r02.x; P0.i4[1] = r13.x; P0.i4[2] = r02.y; P0.i4[3] = r13.y;
        P1.i4[0] = r46.x; P1.i4[1] = r57.x; P1.i4[2] = r46.y; P1.i4[3] = r57.y;

        // V^T A-frags from frag-major LDS (dense, conflict-free)
        short8 va00 = *(const short8*)(cbuf + loff);
        short8 va01 = *(const short8*)(cbuf + loff + 512);
        short8 va10 = *(const short8*)(cbuf + loff + 2048);
        short8 va11 = *(const short8*)(cbuf + loff + 2048 + 512);

        acc0 = __builtin_amdgcn_mfma_f32_32x32x16_bf16(va00, P0.s8, acc0, 0, 0, 0);
        acc1 = __builtin_amdgcn_mfma_f32_32x32x16_bf16(va01, P0.s8, acc1, 0, 0, 0);
        acc0 = __builtin_amdgcn_mfma_f32_32x32x16_bf16(va10, P1.s8, acc0, 0, 0, 0);
        acc1 = __builtin_amdgcn_mfma_f32_32x32x16_bf16(va11, P1.s8, acc1, 0, 0, 0);

        kcur = knext;
    }

    // per-query denominator: lane halves hold complementary key sets
    lsum += __shfl_xor(lsum, 32);
    float inv = gm / lsum;   // fold gamma

#pragma unroll
    for (int r = 0; r < 16; ++r) {
        int o = (r & 3) + 8 * (r >> 2) + 4 * hi;
        size_t i0 = ((size_t)(b * CC + o)) * NN + q0 + ql;
        out[i0] = acc0[r] * inv + x[i0];
        size_t i1 = i0 + (size_t)32 * NN;
        out[i1] = acc1[r] * inv + x[i1];
    }
}

extern "C" void kernel_launch(void* const* d_in, const int* in_sizes, int n_in,
                              void* d_out, int out_size, void* d_ws, size_t ws_size,
                              hipStream_t stream) {
    const float* x     = (const float*)d_in[0];
    const float* Wq    = (const float*)d_in[1];
    const float* Wk    = (const float*)d_in[2];
    const float* Wv    = (const float*)d_in[3];
    const float* gamma = (const float*)d_in[4];
    float* out = (float*)d_out;

    // ws: q f32 [B*8*N] (2MB) | ktr bf16 [B*N*16] (2MB) | v bf16 [B*C*N] (8MB)
    float*  qws = (float*)d_ws;
    ushort* ktr = (ushort*)(qws + (size_t)BATCH * MIDD * NN);
    ushort* vws = ktr + (size_t)BATCH * NN * 16;

    proj_kernel<<<dim3((BATCH * NN) / 64), dim3(256), 0, stream>>>(x, Wq, Wk, Wv, qws, ktr, vws);
    attn_kernel<<<dim3((BATCH * NN) / 128), dim3(256), 0, stream>>>(qws, ktr, vws, x, gamma, out);
}

// Round 5
// 159.882 us; speedup vs baseline: 9.8500x; 1.8894x over previous
//
#include <hip/hip_runtime.h>
#include <hip/hip_bf16.h>

#define BATCH 16
#define CC    64
#define NN    4096
#define MIDD  8

typedef __attribute__((ext_vector_type(8)))  short short8;
typedef __attribute__((ext_vector_type(16))) float f32x16;
typedef __attribute__((ext_vector_type(2)))  int   v2i;

static __device__ __forceinline__ ushort f2bf(float f) {
    return __bfloat16_as_ushort(__float2bfloat16(f));   // RNE
}

static __device__ __forceinline__ void glds16(const void* g, void* l) {
    __builtin_amdgcn_global_load_lds(
        (const __attribute__((address_space(1))) unsigned int*)g,
        (__attribute__((address_space(3))) unsigned int*)l, 16, 0, 0);
}

// ---------------- projection ------------------------------------------------
// x:[B][C][N] f32 -> qtr:[B][N][8] bf16 (scale folded), ktr:[B][N][16] bf16
// (m 8..15 = 0), v:[B][C][N] bf16.
// 1024 blocks x 256 thr; all 4 waves share the same 64 columns, split the
// 80 output rows 20/20/20/20. W read via wave-uniform s_load (scalar pipe).
// Spill-proof: xv[16]/acc[20] only, all statically indexed.
__global__ __launch_bounds__(256) void proj_kernel(
    const float* __restrict__ x,
    const float* __restrict__ Wq,
    const float* __restrict__ Wk,
    const float* __restrict__ Wv,
    ushort* __restrict__ qtr,
    ushort* __restrict__ ktr,
    ushort* __restrict__ v)
{
    int tid = threadIdx.x;
    int wv  = tid >> 6;
    int nl  = tid & 63;
    int g   = blockIdx.x * 64 + nl;
    int b   = g >> 12;
    int n   = g & (NN - 1);
    int wvu = __builtin_amdgcn_readfirstlane(wv);   // SGPR -> uniform W indexing

    const float* xp = x + (size_t)b * CC * NN + n;

    float acc[20];
#pragma unroll
    for (int i = 0; i < 20; ++i) acc[i] = 0.f;

#pragma unroll 1
    for (int cc = 0; cc < 64; cc += 16) {
        float xv[16];
#pragma unroll
        for (int i = 0; i < 16; ++i) xv[i] = xp[(size_t)(cc + i) * NN];

        if (wvu == 0) {
#pragma unroll
            for (int m = 0; m < 8; ++m) {
                const float* w = Wq + m * 64 + cc;
                float a = acc[m];
#pragma unroll
                for (int i = 0; i < 16; ++i) a += w[i] * xv[i];
                acc[m] = a;
            }
#pragma unroll
            for (int m = 0; m < 8; ++m) {
                const float* w = Wk + m * 64 + cc;
                float a = acc[8 + m];
#pragma unroll
                for (int i = 0; i < 16; ++i) a += w[i] * xv[i];
                acc[8 + m] = a;
            }
#pragma unroll
            for (int m = 0; m < 4; ++m) {
                const float* w = Wv + m * 64 + cc;
                float a = acc[16 + m];
#pragma unroll
                for (int i = 0; i < 16; ++i) a += w[i] * xv[i];
                acc[16 + m] = a;
            }
        } else {
            int rb = wvu * 20 - 16;                 // 24 / 44 / 64 -> rows 4..63
#pragma unroll
            for (int m = 0; m < 20; ++m) {
                const float* w = Wv + (rb + m) * 64 + cc;
                float a = acc[m];
#pragma unroll
                for (int i = 0; i < 16; ++i) a += w[i] * xv[i];
                acc[m] = a;
            }
        }
    }

    // fold 1/sqrt(8)*log2(e) into Q here
    const float SCLQ = 0.35355339059327373f * 1.4426950408889634f;
    if (wvu == 0) {
        union { short8 s8; ushort us[8]; } qb;
#pragma unroll
        for (int m = 0; m < 8; ++m) qb.us[m] = f2bf(acc[m] * SCLQ);
        *(short8*)(qtr + ((size_t)b * NN + n) * 8) = qb.s8;

        union { uint4 u4[2]; ushort us[16]; } kb2;
#pragma unroll
        for (int m = 0; m < 8; ++m) kb2.us[m] = f2bf(acc[8 + m]);
#pragma unroll
        for (int m = 8; m < 16; ++m) kb2.us[m] = 0;
        ushort* kd = ktr + ((size_t)b * NN + n) * 16;
        *(uint4*)kd       = kb2.u4[0];
        *(uint4*)(kd + 8) = kb2.u4[1];
#pragma unroll
        for (int i = 0; i < 4; ++i)
            v[((size_t)b * CC + i) * NN + n] = f2bf(acc[16 + i]);
    } else {
        int rb = wvu * 20 - 16;
#pragma unroll
        for (int i = 0; i < 20; ++i)
            v[((size_t)b * CC + rb + i) * NN + n] = f2bf(acc[i]);
    }
}

// ---------------- fused flash attention (all-MFMA) + gamma*out + x ----------
// 512 blocks x 4 waves; wave owns 32 queries; 32-key chunks; 32x32x16 MFMA.
// V+K staged via glds16: coalesced source (4-lane groups read one 64B row
// segment), 2-bit XOR swizzle applied on the GLOBAL source + on LDS reads
// (linear glds16 dest). Depth-2 prefetch, 3 buffers, counted vmcnt.
__global__ __launch_bounds__(256, 2) void attn_kernel(
    const ushort* __restrict__ qtr,
    const ushort* __restrict__ ktr,
    const ushort* __restrict__ v,
    const float*  __restrict__ x,
    const float*  __restrict__ gamma,
    float* __restrict__ out)
{
    __shared__ __align__(16) char lds[3 * 5120];   // per buffer: V 4KB + K 1KB

    int bid = blockIdx.x;
    int wg  = (bid & 7) * 64 + (bid >> 3);   // bijective XCD swizzle (512%8==0)
    int b   = wg >> 5;
    int qt  = wg & 31;

    int tid  = threadIdx.x;
    int wv   = tid >> 6;
    int lane = tid & 63;
    int hi   = lane >> 5;
    int ql   = lane & 31;
    int q0   = qt * 128 + wv * 32;

    // ---- register globals FIRST, then drain, so the loop has no pending
    // register loads the waitcnt pass could get conservative about.
    short8 qf = *(const short8*)(qtr + ((size_t)b * NN + q0 + ql) * 8);
    float  gm = gamma[0];
    short8 zero8 = {};
    if (hi) qf = zero8;    // B-frag rows m=8..15 are the zero pad
    asm volatile("s_waitcnt vmcnt(0)" ::: "memory");

    const ushort* kb_ = ktr + (size_t)b * NN * 16;
    const ushort* vb_ = v   + (size_t)b * CC * NN;

    // staging: thread t -> phys granule t. o = t>>2; logical key-slot is
    // (t&3)^(o&3) so that reads at (4o + (ks^(o&3))) see logical (o,ks).
    int so   = tid >> 2;
    int sksl = (tid & 3) ^ (so & 3);
    const ushort* vsrc0 = vb_ + (size_t)so * NN + sksl * 8;
    const ushort* ksrc0 = kb_ + (tid >> 1) * 16 + (tid & 1) * 8;  // tid<64 only
    int vdsto = tid * 16;
    int kdsto = 4096 + tid * 16;

    // read offsets (bytes)
    int swz  = ql & 3;
    int g00  = (4 * ql + (hi ^ swz)) * 16;          // keys 0..15 half
    int g10  = (4 * ql + ((2 + hi) ^ swz)) * 16;    // keys 16..31 half
    int koff = 4096 + (2 * ql + hi) * 16;

    char* b0 = lds;
    char* b1 = lds + 5120;
    char* b2 = lds + 10240;

    f32x16 zf   = {};
    f32x16 acc0 = {};
    f32x16 acc1 = {};
    float  lsum = 0.f;

    // prologue: stage tiles 0 and 1
    glds16(vsrc0, b0 + vdsto);
    if (wv == 0) glds16(ksrc0, b0 + kdsto);
    glds16(vsrc0 + 32, b1 + vdsto);
    if (wv == 0) glds16(ksrc0 + 32 * 16, b1 + kdsto);

    for (int t = 0; t < 128; ++t) {
        int k2 = ((t + 2) & 127) * 32;   // wraps harmlessly on last 2 iters

        __builtin_amdgcn_s_barrier();               // all done reading b2's old tile
        glds16(vsrc0 + k2, b2 + vdsto);
        if (wv == 0) {
            glds16(ksrc0 + (size_t)k2 * 16, b2 + kdsto);
            asm volatile("s_waitcnt vmcnt(4)" ::: "memory");  // tile t done (mine)
        } else {
            asm volatile("s_waitcnt vmcnt(2)" ::: "memory");
        }
        __builtin_amdgcn_s_barrier();               // tile t visible from all waves
        __builtin_amdgcn_sched_barrier(0);

        // S^T[key][q]: A = K[32key x 16m] (m 8..15 zero), B = Q
        short8 kfrag = *(const short8*)(b0 + koff);
        f32x16 s = __builtin_amdgcn_mfma_f32_32x32x16_bf16(kfrag, qf, zf, 0, 0, 0);

        float p[16];
#pragma unroll
        for (int r = 0; r < 16; ++r) p[r] = __builtin_amdgcn_exp2f(s[r]);
        float t0 = (p[0] + p[1]) + (p[2] + p[3]);
        float t1 = (p[4] + p[5]) + (p[6] + p[7]);
        float t2 = (p[8] + p[9]) + (p[10] + p[11]);
        float t3 = (p[12] + p[13]) + (p[14] + p[15]);
        lsum += (t0 + t1) + (t2 + t3);

        unsigned u[8];
#pragma unroll
        for (int i = 0; i < 8; ++i)
            asm("v_cvt_pk_bf16_f32 %0, %1, %2"
                : "=v"(u[i]) : "v"(p[2 * i]), "v"(p[2 * i + 1]));

        // redistribute to PV B-frag layout (one swap fills two words)
        v2i r02 = __builtin_amdgcn_permlane32_swap(u[0], u[2], false, false);
        v2i r13 = __builtin_amdgcn_permlane32_swap(u[1], u[3], false, false);
        v2i r46 = __builtin_amdgcn_permlane32_swap(u[4], u[6], false, false);
        v2i r57 = __builtin_amdgcn_permlane32_swap(u[5], u[7], false, false);
        union { short8 s8; int i4[4]; } P0, P1;
        P0.i4[0] = r02.x; P0.i4[1] = r13.x; P0.i4[2] = r02.y; P0.i4[3] = r13.y;
        P1.i4[0] = r46.x; P1.i4[1] = r57.x; P1.i4[2] = r46.y; P1.i4[3] = r57.y;

        // V^T A-frags (swizzled reads)
        short8 va00 = *(const short8*)(b0 + g00);
        short8 va01 = *(const short8*)(b0 + 2048 + g00);
        short8 va10 = *(const short8*)(b0 + g10);
        short8 va11 = *(const short8*)(b0 + 2048 + g10);

        __builtin_amdgcn_s_setprio(1);
        acc0 = __builtin_amdgcn_mfma_f32_32x32x16_bf16(va00, P0.s8, acc0, 0, 0, 0);
        acc1 = __builtin_amdgcn_mfma_f32_32x32x16_bf16(va01, P0.s8, acc1, 0, 0, 0);
        acc0 = __builtin_amdgcn_mfma_f32_32x32x16_bf16(va10, P1.s8, acc0, 0, 0, 0);
        acc1 = __builtin_amdgcn_mfma_f32_32x32x16_bf16(va11, P1.s8, acc1, 0, 0, 0);
        __builtin_amdgcn_s_setprio(0);

        char* tp = b0; b0 = b1; b1 = b2; b2 = tp;   // rotate 3-deep
    }

    // per-query denominator: lane halves hold complementary key sets
    lsum += __shfl_xor(lsum, 32);
    float inv = gm / lsum;   // fold gamma

#pragma unroll
    for (int r = 0; r < 16; ++r) {
        int o = (r & 3) + 8 * (r >> 2) + 4 * hi;
        size_t i0 = ((size_t)(b * CC + o)) * NN + q0 + ql;
        out[i0] = acc0[r] * inv + x[i0];
        size_t i1 = i0 + (size_t)32 * NN;
        out[i1] = acc1[r] * inv + x[i1];
    }
}

extern "C" void kernel_launch(void* const* d_in, const int* in_sizes, int n_in,
                              void* d_out, int out_size, void* d_ws, size_t ws_size,
                              hipStream_t stream) {
    const float* x     = (const float*)d_in[0];
    const float* Wq    = (const float*)d_in[1];
    const float* Wk    = (const float*)d_in[2];
    const float* Wv    = (const float*)d_in[3];
    const float* gamma = (const float*)d_in[4];
    float* out = (float*)d_out;

    // ws: qtr bf16 [B*N*8] (1MB) | ktr bf16 [B*N*16] (2MB) | v bf16 [B*C*N] (8MB)
    ushort* qtr = (ushort*)d_ws;
    ushort* ktr = qtr + (size_t)BATCH * NN * 8;
    ushort* vws = ktr + (size_t)BATCH * NN * 16;

    proj_kernel<<<dim3((BATCH * NN) / 64), dim3(256), 0, stream>>>(x, Wq, Wk, Wv, qtr, ktr, vws);
    attn_kernel<<<dim3((BATCH * NN) / 128), dim3(256), 0, stream>>>(qtr, ktr, vws, x, gamma, out);
}

// Round 6
// 158.224 us; speedup vs baseline: 9.9533x; 1.0105x over previous
//
#include <hip/hip_runtime.h>
#include <hip/hip_bf16.h>

#define BATCH 16
#define CC    64
#define NN    4096
#define MIDD  8

typedef __attribute__((ext_vector_type(8)))  short short8;
typedef __attribute__((ext_vector_type(16))) float f32x16;
typedef __attribute__((ext_vector_type(2)))  int   v2i;

static __device__ __forceinline__ ushort f2bf(float f) {
    return __bfloat16_as_ushort(__float2bfloat16(f));   // RNE
}

static __device__ __forceinline__ void glds16(const void* g, void* l) {
    __builtin_amdgcn_global_load_lds(
        (const __attribute__((address_space(1))) unsigned int*)g,
        (__attribute__((address_space(3))) unsigned int*)l, 16, 0, 0);
}

// ---------------- projection ------------------------------------------------
// x:[B][C][N] f32 -> qtr:[B][N][8] bf16 (scale folded), ktr:[B][N][16] bf16
// (m 8..15 = 0), v:[B][C][N] bf16.
// 1024 blocks x 256 thr; 4 waves share 64 columns, split 80 output rows
// 20/20/20/20. Weights staged ONCE in LDS; each wave reads its contiguous
// 20-row slice via ds_read_b128 broadcast (uniform addr -> conflict-free).
__global__ __launch_bounds__(256) void proj_kernel(
    const float* __restrict__ x,
    const float* __restrict__ Wq,
    const float* __restrict__ Wk,
    const float* __restrict__ Wv,
    ushort* __restrict__ qtr,
    ushort* __restrict__ ktr,
    ushort* __restrict__ v)
{
    __shared__ __align__(16) float sW[80 * 64];   // rows: Wq(8) | Wk(8) | Wv(64)

    int tid = threadIdx.x;
    for (int i = tid; i < 512; i += 256) { sW[i] = Wq[i]; sW[512 + i] = Wk[i]; }
    for (int i = tid; i < 4096; i += 256) sW[1024 + i] = Wv[i];
    __syncthreads();

    int wv = tid >> 6;
    int nl = tid & 63;
    int g  = blockIdx.x * 64 + nl;
    int b  = g >> 12;
    int n  = g & (NN - 1);

    const float* xp = x + (size_t)b * CC * NN + n;
    const float* wb = sW + wv * 20 * 64;          // wave's contiguous row slice

    float acc[20];
#pragma unroll
    for (int i = 0; i < 20; ++i) acc[i] = 0.f;

#pragma unroll 1
    for (int cc = 0; cc < 64; cc += 16) {
        float xv[16];
#pragma unroll
        for (int i = 0; i < 16; ++i) xv[i] = xp[(size_t)(cc + i) * NN];

#pragma unroll
        for (int m = 0; m < 20; ++m) {
            const float4* w4 = (const float4*)(wb + m * 64 + cc);
            float4 w0 = w4[0], w1 = w4[1], w2 = w4[2], w3 = w4[3];
            float a = acc[m];
            a += w0.x * xv[0]  + w0.y * xv[1]  + w0.z * xv[2]  + w0.w * xv[3];
            a += w1.x * xv[4]  + w1.y * xv[5]  + w1.z * xv[6]  + w1.w * xv[7];
            a += w2.x * xv[8]  + w2.y * xv[9]  + w2.z * xv[10] + w2.w * xv[11];
            a += w3.x * xv[12] + w3.y * xv[13] + w3.z * xv[14] + w3.w * xv[15];
            acc[m] = a;
        }
    }

    const float SCLQ = 0.35355339059327373f * 1.4426950408889634f;
    if (wv == 0) {
        union { short8 s8; ushort us[8]; } qb;
#pragma unroll
        for (int m = 0; m < 8; ++m) qb.us[m] = f2bf(acc[m] * SCLQ);
        *(short8*)(qtr + ((size_t)b * NN + n) * 8) = qb.s8;

        union { uint4 u4[2]; ushort us[16]; } kb2;
#pragma unroll
        for (int m = 0; m < 8; ++m) kb2.us[m] = f2bf(acc[8 + m]);
#pragma unroll
        for (int m = 8; m < 16; ++m) kb2.us[m] = 0;
        ushort* kd = ktr + ((size_t)b * NN + n) * 16;
        *(uint4*)kd       = kb2.u4[0];
        *(uint4*)(kd + 8) = kb2.u4[1];
#pragma unroll
        for (int i = 0; i < 4; ++i)
            v[((size_t)b * CC + i) * NN + n] = f2bf(acc[16 + i]);
    } else {
        int rb = wv * 20 - 16;                    // 24/44/64 -> rows 4..63
#pragma unroll
        for (int i = 0; i < 20; ++i)
            v[((size_t)b * CC + rb + i) * NN + n] = f2bf(acc[i]);
    }
}

// ---------------- fused flash attention (all-MFMA) + gamma*out + x ----------
// 512 blocks x 4 waves; wave owns 32 queries; 32-key chunks; 32x32x16 MFMA.
// LDS (per 5KB buffer): V 4KB as granules g=4o+s_phys, s_phys = s_log^((o>>1)&3)
// -> frag reads hit all 8 bank-groups per 16-lane cohort; K 1KB as [mh][key].
// glds16 dest linear; swizzle applied on global SOURCE + on LDS reads.
// Depth-2 prefetch, 3 buffers, counted vmcnt. Softmax denominator via
// mfma(ones, P) on the idle matrix pipe (consistent with bf16 numerator).
__global__ __launch_bounds__(256, 2) void attn_kernel(
    const ushort* __restrict__ qtr,
    const ushort* __restrict__ ktr,
    const ushort* __restrict__ v,
    const float*  __restrict__ x,
    const float*  __restrict__ gamma,
    float* __restrict__ out)
{
    __shared__ __align__(16) char lds[3 * 5120];

    int bid = blockIdx.x;
    int wg  = (bid & 7) * 64 + (bid >> 3);   // bijective XCD swizzle (512%8==0)
    int b   = wg >> 5;
    int qt  = wg & 31;

    int tid  = threadIdx.x;
    int wv   = tid >> 6;
    int lane = tid & 63;
    int hi   = lane >> 5;
    int ql   = lane & 31;
    int q0   = qt * 128 + wv * 32;

    // register globals first, then drain, so the loop's waitcnts stay exact
    short8 qf = *(const short8*)(qtr + ((size_t)b * NN + q0 + ql) * 8);
    float  gm = gamma[0];
    short8 zero8 = {};
    if (hi) qf = zero8;                      // B-frag rows m=8..15 = zero pad
    asm volatile("s_waitcnt vmcnt(0)" ::: "memory");

    const ushort* kb_ = ktr + (size_t)b * NN * 16;
    const ushort* vb_ = v   + (size_t)b * CC * NN;

    // staging: thread t -> phys granule t (linear dest).
    // V: o = t>>2, s_phys = t&3, s_log = s_phys ^ ((o>>1)&3)
    int so   = tid >> 2;
    int slog = (tid & 3) ^ ((so >> 1) & 3);
    const ushort* vsrc0 = vb_ + (size_t)so * NN + slog * 8;
    // K (tid<64 only): granule t -> mh = t>>5, key = t&31
    const ushort* ksrc0 = kb_ + (size_t)(tid & 31) * 16 + (tid >> 5) * 8;
    int vdsto = tid * 16;
    int kdsto = 4096 + tid * 16;

    // read offsets (bytes); x0 = read-side XOR
    int x0  = (ql >> 1) & 3;
    int gA0 = (4 * ql + (hi ^ x0)) * 16;             // o=ql,    keys 0..15
    int gA1 = (4 * ql + ((2 + hi) ^ x0)) * 16;       // o=ql,    keys 16..31
    int gB0 = 2048 + gA0;                            // o=32+ql, keys 0..15
    int gB1 = 2048 + gA1;                            // o=32+ql, keys 16..31
    int koff = 4096 + (hi * 32 + ql) * 16;           // [mh][key]

    char* b0 = lds;
    char* b1 = lds + 5120;
    char* b2 = lds + 10240;

    // bf16 ones A-frag for the denominator MFMA
    union { short8 s8; ushort us[8]; } onesu;
#pragma unroll
    for (int i = 0; i < 8; ++i) onesu.us[i] = 0x3F80;
    short8 ones = onesu.s8;

    f32x16 zf   = {};
    f32x16 acc0 = {};
    f32x16 acc1 = {};
    f32x16 accl = {};

    // prologue: stage tiles 0 and 1
    glds16(vsrc0, b0 + vdsto);
    if (wv == 0) glds16(ksrc0, b0 + kdsto);
    glds16(vsrc0 + 32, b1 + vdsto);
    if (wv == 0) glds16(ksrc0 + 32 * 16, b1 + kdsto);

    for (int t = 0; t < 128; ++t) {
        int k2 = ((t + 2) & 127) * 32;   // wraps harmlessly on last 2 iters

        __builtin_amdgcn_s_barrier();               // all done reading b2's old tile
        glds16(vsrc0 + k2, b2 + vdsto);
        if (wv == 0) {
            glds16(ksrc0 + (size_t)k2 * 16, b2 + kdsto);
            asm volatile("s_waitcnt vmcnt(4)" ::: "memory");  // my tile-t loads done
        } else {
            asm volatile("s_waitcnt vmcnt(2)" ::: "memory");
        }
        __builtin_amdgcn_s_barrier();               // tile t visible from all waves
        __builtin_amdgcn_sched_barrier(0);

        // S^T[key][q]: A = K[32key x 16m] (m 8..15 zero), B = Q
        short8 kfrag = *(const short8*)(b0 + koff);
        f32x16 s = __builtin_amdgcn_mfma_f32_32x32x16_bf16(kfrag, qf, zf, 0, 0, 0);

        float p[16];
#pragma unroll
        for (int r = 0; r < 16; ++r) p[r] = __builtin_amdgcn_exp2f(s[r]);

        unsigned u[8];
#pragma unroll
        for (int i = 0; i < 8; ++i)
            asm("v_cvt_pk_bf16_f32 %0, %1, %2"
                : "=v"(u[i]) : "v"(p[2 * i]), "v"(p[2 * i + 1]));

        // redistribute to PV B-frag layout (one swap fills two words)
        v2i r02 = __builtin_amdgcn_permlane32_swap(u[0], u[2], false, false);
        v2i r13 = __builtin_amdgcn_permlane32_swap(u[1], u[3], false, false);
        v2i r46 = __builtin_amdgcn_permlane32_swap(u[4], u[6], false, false);
        v2i r57 = __builtin_amdgcn_permlane32_swap(u[5], u[7], false, false);
        union { short8 s8; int i4[4]; } P0, P1;
        P0.i4[0] = r02.x; P0.i4[1] = r13.x; P0.i4[2] = r02.y; P0.i4[3] = r13.y;
        P1.i4[0] = r46.x; P1.i4[1] = r57.x; P1.i4[2] = r46.y; P1.i4[3] = r57.y;

        // V^T A-frags (swizzled reads, conflict-free)
        short8 vaA0 = *(const short8*)(b0 + gA0);
        short8 vaA1 = *(const short8*)(b0 + gA1);
        short8 vaB0 = *(const short8*)(b0 + gB0);
        short8 vaB1 = *(const short8*)(b0 + gB1);

        __builtin_amdgcn_s_setprio(1);
        acc0 = __builtin_amdgcn_mfma_f32_32x32x16_bf16(vaA0, P0.s8, acc0, 0, 0, 0);
        acc1 = __builtin_amdgcn_mfma_f32_32x32x16_bf16(vaB0, P0.s8, acc1, 0, 0, 0);
        accl = __builtin_amdgcn_mfma_f32_32x32x16_bf16(ones, P0.s8, accl, 0, 0, 0);
        acc0 = __builtin_amdgcn_mfma_f32_32x32x16_bf16(vaA1, P1.s8, acc0, 0, 0, 0);
        acc1 = __builtin_amdgcn_mfma_f32_32x32x16_bf16(vaB1, P1.s8, acc1, 0, 0, 0);
        accl = __builtin_amdgcn_mfma_f32_32x32x16_bf16(ones, P1.s8, accl, 0, 0, 0);
        __builtin_amdgcn_s_setprio(0);

        char* tp = b0; b0 = b1; b1 = b2; b2 = tp;   // rotate 3-deep
    }

    // denominator: every accl row = sum over ALL keys for this lane's q
    float inv = gm / accl[0];

#pragma unroll
    for (int r = 0; r < 16; ++r) {
        int o = (r & 3) + 8 * (r >> 2) + 4 * hi;
        size_t i0 = ((size_t)(b * CC + o)) * NN + q0 + ql;
        out[i0] = acc0[r] * inv + x[i0];
        size_t i1 = i0 + (size_t)32 * NN;
        out[i1] = acc1[r] * inv + x[i1];
    }
}

extern "C" void kernel_launch(void* const* d_in, const int* in_sizes, int n_in,
                              void* d_out, int out_size, void* d_ws, size_t ws_size,
                              hipStream_t stream) {
    const float* x     = (const float*)d_in[0];
    const float* Wq    = (const float*)d_in[1];
    const float* Wk    = (const float*)d_in[2];
    const float* Wv    = (const float*)d_in[3];
    const float* gamma = (const float*)d_in[4];
    float* out = (float*)d_out;

    // ws: qtr bf16 [B*N*8] (1MB) | ktr bf16 [B*N*16] (2MB) | v bf16 [B*C*N] (8MB)
    ushort* qtr = (ushort*)d_ws;
    ushort* ktr = qtr + (size_t)BATCH * NN * 8;
    ushort* vws = ktr + (size_t)BATCH * NN * 16;

    proj_kernel<<<dim3((BATCH * NN) / 64), dim3(256), 0, stream>>>(x, Wq, Wk, Wv, qtr, ktr, vws);
    attn_kernel<<<dim3((BATCH * NN) / 128), dim3(256), 0, stream>>>(qtr, ktr, vws, x, gamma, out);
}

// Round 7
// 144.336 us; speedup vs baseline: 10.9110x; 1.0962x over previous
//
#include <hip/hip_runtime.h>
#include <hip/hip_bf16.h>

#define BATCH 16
#define CC    64
#define NN    4096
#define MIDD  8

typedef __attribute__((ext_vector_type(8)))  short short8;
typedef __attribute__((ext_vector_type(16))) float f32x16;
typedef __attribute__((ext_vector_type(2)))  int   v2i;

static __device__ __forceinline__ ushort f2bf(float f) {
    return __bfloat16_as_ushort(__float2bfloat16(f));   // RNE
}

static __device__ __forceinline__ void glds16(const void* g, void* l) {
    __builtin_amdgcn_global_load_lds(
        (const __attribute__((address_space(1))) unsigned int*)g,
        (__attribute__((address_space(3))) unsigned int*)l, 16, 0, 0);
}

static __device__ __forceinline__ unsigned cvt_pk(float lo, float hi) {
    unsigned r;
    asm("v_cvt_pk_bf16_f32 %0, %1, %2" : "=v"(r) : "v"(lo), "v"(hi));
    return r;
}

// ---------------- projection via MFMA --------------------------------------
// D[96pad(80) rows][64 n] = W * x  per block (1 batch x 64 cols).
// Rows: 0-7 Wq -> qtr[B][N][8] (SCLQ folded at epilogue), 8-15 Wk ->
// ktr[B][N][16] (zero pad), 16-79 Wv -> v[B][C][N].
// x transposed through LDS: coalesced f32 reads -> cvt_pk pairs ->
// ds_write_b32 at dword (c/2)^(n&31) (conflict-free write+read).
// Wave split: w0:(s0,t01) w1:(s1,t01) w2:(s0,t2) w3:(s1,t2).
__global__ __launch_bounds__(256) void proj_kernel(
    const float* __restrict__ x,
    const float* __restrict__ Wq,
    const float* __restrict__ Wk,
    const float* __restrict__ Wv,
    ushort* __restrict__ qtr,
    ushort* __restrict__ ktr,
    ushort* __restrict__ v)
{
    __shared__ unsigned xT[64 * 32];   // [n][dw phys], 8 KB

    int tid = threadIdx.x;
    int b   = blockIdx.x >> 6;
    int n0  = (blockIdx.x & 63) * 64;

    // ---- stage x-tile transposed into LDS
    {
        int n  = tid & 63;
        int cp = tid >> 6;                       // c-pair base 0..3
        const float* xb = x + (size_t)b * CC * NN + n0 + n;
#pragma unroll
        for (int rep = 0; rep < 8; ++rep) {
            int c = cp * 2 + rep * 8;
            float a0 = xb[(size_t)c * NN];
            float a1 = xb[(size_t)(c + 1) * NN];
            int dwlog = cp + rep * 4;            // = c/2
            xT[n * 32 + (dwlog ^ (n & 31))] = cvt_pk(a0, a1);
        }
    }

    int wv   = tid >> 6;
    int lane = tid & 63;
    int hi   = lane >> 5;
    int r    = lane & 31;
    int s_   = wv & 1;                           // n-subtile 0/1
    bool hiT = wv >= 2;                          // handles row-tile 2

    // ---- W A-frags (bf16), loaded while staging is in flight
    short8 wfa[4], wfb[4];                       // t0,t1 (lo waves) / t2 (hi waves)
    if (!hiT) {
        const float* r0 = (r < 8)  ? (Wq + r * 64)
                        : (r < 16) ? (Wk + (r - 8) * 64)
                                   : (Wv + (r - 16) * 64);
        const float* r1 = Wv + (16 + r) * 64;    // rows 32..63 -> v ch 16..47
#pragma unroll
        for (int kc = 0; kc < 4; ++kc) {
            const float4* p0 = (const float4*)(r0 + kc * 16 + hi * 8);
            const float4* p1 = (const float4*)(r1 + kc * 16 + hi * 8);
            float4 a = p0[0], c4 = p0[1];
            float4 e = p1[0], g4 = p1[1];
            union { short8 s8; unsigned u[4]; } wa, wb;
            wa.u[0] = cvt_pk(a.x, a.y);  wa.u[1] = cvt_pk(a.z, a.w);
            wa.u[2] = cvt_pk(c4.x, c4.y); wa.u[3] = cvt_pk(c4.z, c4.w);
            wb.u[0] = cvt_pk(e.x, e.y);  wb.u[1] = cvt_pk(e.z, e.w);
            wb.u[2] = cvt_pk(g4.x, g4.y); wb.u[3] = cvt_pk(g4.z, g4.w);
            wfa[kc] = wa.s8; wfb[kc] = wb.s8;
        }
    } else {
        const float* r2 = Wv + (size_t)(r < 16 ? (48 + r) : 48) * 64;
        short8 z8 = {};
#pragma unroll
        for (int kc = 0; kc < 4; ++kc) {
            const float4* p2 = (const float4*)(r2 + kc * 16 + hi * 8);
            float4 a = p2[0], c4 = p2[1];
            union { short8 s8; unsigned u[4]; } wa;
            wa.u[0] = cvt_pk(a.x, a.y);  wa.u[1] = cvt_pk(a.z, a.w);
            wa.u[2] = cvt_pk(c4.x, c4.y); wa.u[3] = cvt_pk(c4.z, c4.w);
            wfa[kc] = (r < 16) ? wa.s8 : z8;     // pad rows 80..95 = 0
            wfb[kc] = z8;
        }
    }

    __syncthreads();

    // ---- B-frags from transposed LDS (swizzled, conflict-free)
    short8 bf[4];
    int nr = s_ * 32 + r;
#pragma unroll
    for (int kc = 0; kc < 4; ++kc) {
        union { short8 s8; unsigned u[4]; } bu;
#pragma unroll
        for (int i = 0; i < 4; ++i) {
            int dwlog = kc * 8 + hi * 4 + i;
            bu.u[i] = xT[nr * 32 + (dwlog ^ r)];
        }
        bf[kc] = bu.s8;
    }

    int ng = n0 + s_ * 32 + r;                   // this lane's output column
    size_t nb = (size_t)b * NN + ng;
    const float SCLQ = 0.35355339059327373f * 1.4426950408889634f;

    if (!hiT) {
        // tile 0: rows 0..31 (q, k, v ch 0..15)
        f32x16 acc = {};
#pragma unroll
        for (int kc = 0; kc < 4; ++kc)
            acc = __builtin_amdgcn_mfma_f32_32x32x16_bf16(wfa[kc], bf[kc], acc, 0, 0, 0);
        uint2 qd, kd, zd; zd.x = 0; zd.y = 0;
        qd.x = cvt_pk(acc[0] * SCLQ, acc[1] * SCLQ);
        qd.y = cvt_pk(acc[2] * SCLQ, acc[3] * SCLQ);
        kd.x = cvt_pk(acc[4], acc[5]);
        kd.y = cvt_pk(acc[6], acc[7]);
        *(uint2*)(qtr + nb * 8 + hi * 4) = qd;
        *(uint2*)(ktr + nb * 16 + hi * 4) = kd;
        *(uint2*)(ktr + nb * 16 + 8 + hi * 4) = zd;
#pragma unroll
        for (int reg = 8; reg < 16; ++reg) {
            int ch = (reg & 3) + 8 * ((reg >> 2) - 2) + 4 * hi;
            v[((size_t)b * CC + ch) * NN + ng] = f2bf(acc[reg]);
        }
        // tile 1: rows 32..63 -> v ch 16..47
        f32x16 ac1 = {};
#pragma unroll
        for (int kc = 0; kc < 4; ++kc)
            ac1 = __builtin_amdgcn_mfma_f32_32x32x16_bf16(wfb[kc], bf[kc], ac1, 0, 0, 0);
#pragma unroll
        for (int reg = 0; reg < 16; ++reg) {
            int ch = 16 + (reg & 3) + 8 * (reg >> 2) + 4 * hi;
            v[((size_t)b * CC + ch) * NN + ng] = f2bf(ac1[reg]);
        }
    } else {
        // tile 2: rows 64..79 -> v ch 48..63 (regs 8..15 are pad)
        f32x16 acc = {};
#pragma unroll
        for (int kc = 0; kc < 4; ++kc)
            acc = __builtin_amdgcn_mfma_f32_32x32x16_bf16(wfa[kc], bf[kc], acc, 0, 0, 0);
#pragma unroll
        for (int reg = 0; reg < 8; ++reg) {
            int ch = 48 + (reg & 3) + 8 * (reg >> 2) + 4 * hi;
            v[((size_t)b * CC + ch) * NN + ng] = f2bf(acc[reg]);
        }
    }
}

// ---------------- fused flash attention (all-MFMA) + gamma*out + x ----------
// 512 blocks x 4 waves; wave owns 32 q; 64-key iterations (2 chunks per
// barrier pair). V 8KB/tile: granule g = o*8 + (slot ^ (o&7)); K 2KB [mh][key].
// glds16 linear dest; swizzle on global source + LDS reads. 3 buffers,
// depth-2 prefetch, counted per-wave vmcnt (waves 0,1 also stage K).
__global__ __launch_bounds__(256, 2) void attn_kernel(
    const ushort* __restrict__ qtr,
    const ushort* __restrict__ ktr,
    const ushort* __restrict__ v,
    const float*  __restrict__ x,
    const float*  __restrict__ gamma,
    float* __restrict__ out)
{
    __shared__ __align__(16) char lds[3 * 10240];

    int bid = blockIdx.x;
    int wg  = (bid & 7) * 64 + (bid >> 3);   // bijective XCD swizzle (512%8==0)
    int b   = wg >> 5;
    int qt  = wg & 31;

    int tid  = threadIdx.x;
    int wv   = tid >> 6;
    int lane = tid & 63;
    int hi   = lane >> 5;
    int ql   = lane & 31;
    int q0   = qt * 128 + wv * 32;

    short8 qf = *(const short8*)(qtr + ((size_t)b * NN + q0 + ql) * 8);
    float  gm = gamma[0];
    short8 zero8 = {};
    if (hi) qf = zero8;                      // B-frag rows m=8..15 = zero pad
    asm volatile("s_waitcnt vmcnt(0)" ::: "memory");

    const ushort* kb_ = ktr + (size_t)b * NN * 16;
    const ushort* vb_ = v   + (size_t)b * CC * NN;

    // V staging: thread t stages granules t and t+256 (linear dest).
    // granule g: o = g>>3, s_phys = g&7, s_log = s_phys ^ (o&7)
    int oA = tid >> 3, sA = (tid & 7) ^ (oA & 7);
    int oB = oA + 32,  sB = (tid & 7) ^ (oB & 7);
    const ushort* vsrcA = vb_ + (size_t)oA * NN + sA * 8;
    const ushort* vsrcB = vb_ + (size_t)oB * NN + sB * 8;
    // K staging (tid<128): granule t -> mh = t>>6, key = t&63
    const ushort* ksrc0 = kb_ + (size_t)(tid & 63) * 16 + (tid >> 6) * 8;
    int vdA = tid * 16, vdB = (tid + 256) * 16, kd_ = 8192 + tid * 16;

    char* b0 = lds;
    char* b1 = lds + 10240;
    char* b2 = lds + 20480;

    union { short8 s8; ushort us[8]; } onesu;
#pragma unroll
    for (int i = 0; i < 8; ++i) onesu.us[i] = 0x3F80;
    short8 ones = onesu.s8;

    f32x16 zf   = {};
    f32x16 acc0 = {};
    f32x16 acc1 = {};
    f32x16 accl = {};

    // prologue: stage tiles 0 and 1 (64 keys each)
    glds16(vsrcA, b0 + vdA); glds16(vsrcB, b0 + vdB);
    if (wv < 2) glds16(ksrc0, b0 + kd_);
    glds16(vsrcA + 64, b1 + vdA); glds16(vsrcB + 64, b1 + vdB);
    if (wv < 2) glds16(ksrc0 + 64 * 16, b1 + kd_);

    for (int t = 0; t < 64; ++t) {
        int k2 = ((t + 2) & 63) * 64;        // wraps harmlessly on last 2 iters

        __builtin_amdgcn_s_barrier();        // all done reading b2's old tile
        glds16(vsrcA + k2, b2 + vdA);
        glds16(vsrcB + k2, b2 + vdB);
        if (wv < 2) {
            glds16(ksrc0 + (size_t)k2 * 16, b2 + kd_);
            asm volatile("s_waitcnt vmcnt(6)" ::: "memory");  // my tile-t done
        } else {
            asm volatile("s_waitcnt vmcnt(4)" ::: "memory");
        }
        __builtin_amdgcn_s_barrier();        // tile t visible from all waves
        __builtin_amdgcn_sched_barrier(0);

        // K frags for both 32-key chunks
        short8 kf0 = *(const short8*)(b0 + 8192 + (hi * 64 + ql) * 16);
        short8 kf1 = *(const short8*)(b0 + 8192 + (hi * 64 + 32 + ql) * 16);

        // V^T A-frags (swizzled reads): [chunk][frag]
        short8 vA[2][2], vB[2][2];
#pragma unroll
        for (int c = 0; c < 2; ++c)
#pragma unroll
            for (int f = 0; f < 2; ++f) {
                int byteA = (ql * 8 + ((c * 4 + f * 2 + hi) ^ (ql & 7))) * 16;
                vA[c][f] = *(const short8*)(b0 + byteA);
                vB[c][f] = *(const short8*)(b0 + byteA + 4096);
            }

        f32x16 s0 = __builtin_amdgcn_mfma_f32_32x32x16_bf16(kf0, qf, zf, 0, 0, 0);
        f32x16 s1 = __builtin_amdgcn_mfma_f32_32x32x16_bf16(kf1, qf, zf, 0, 0, 0);

#pragma unroll
        for (int c = 0; c < 2; ++c) {
            const f32x16& s = c ? s1 : s0;
            float p[16];
#pragma unroll
            for (int r = 0; r < 16; ++r) p[r] = __builtin_amdgcn_exp2f(s[r]);

            unsigned u[8];
#pragma unroll
            for (int i = 0; i < 8; ++i) u[i] = cvt_pk(p[2 * i], p[2 * i + 1]);

            v2i r02 = __builtin_amdgcn_permlane32_swap(u[0], u[2], false, false);
            v2i r13 = __builtin_amdgcn_permlane32_swap(u[1], u[3], false, false);
            v2i r46 = __builtin_amdgcn_permlane32_swap(u[4], u[6], false, false);
            v2i r57 = __builtin_amdgcn_permlane32_swap(u[5], u[7], false, false);
            union { short8 s8; int i4[4]; } P0, P1;
            P0.i4[0] = r02.x; P0.i4[1] = r13.x; P0.i4[2] = r02.y; P0.i4[3] = r13.y;
            P1.i4[0] = r46.x; P1.i4[1] = r57.x; P1.i4[2] = r46.y; P1.i4[3] = r57.y;

            __builtin_amdgcn_s_setprio(1);
            acc0 = __builtin_amdgcn_mfma_f32_32x32x16_bf16(vA[c][0], P0.s8, acc0, 0, 0, 0);
            acc1 = __builtin_amdgcn_mfma_f32_32x32x16_bf16(vB[c][0], P0.s8, acc1, 0, 0, 0);
            accl = __builtin_amdgcn_mfma_f32_32x32x16_bf16(ones,    P0.s8, accl, 0, 0, 0);
            acc0 = __builtin_amdgcn_mfma_f32_32x32x16_bf16(vA[c][1], P1.s8, acc0, 0, 0, 0);
            acc1 = __builtin_amdgcn_mfma_f32_32x32x16_bf16(vB[c][1], P1.s8, acc1, 0, 0, 0);
            accl = __builtin_amdgcn_mfma_f32_32x32x16_bf16(ones,    P1.s8, accl, 0, 0, 0);
            __builtin_amdgcn_s_setprio(0);
        }

        char* tp = b0; b0 = b1; b1 = b2; b2 = tp;   // rotate 3-deep
    }

    float inv = gm / accl[0];

#pragma unroll
    for (int r = 0; r < 16; ++r) {
        int o = (r & 3) + 8 * (r >> 2) + 4 * hi;
        size_t i0 = ((size_t)(b * CC + o)) * NN + q0 + ql;
        out[i0] = acc0[r] * inv + x[i0];
        size_t i1 = i0 + (size_t)32 * NN;
        out[i1] = acc1[r] * inv + x[i1];
    }
}

extern "C" void kernel_launch(void* const* d_in, const int* in_sizes, int n_in,
                              void* d_out, int out_size, void* d_ws, size_t ws_size,
                              hipStream_t stream) {
    const float* x     = (const float*)d_in[0];
    const float* Wq    = (const float*)d_in[1];
    const float* Wk    = (const float*)d_in[2];
    const float* Wv    = (const float*)d_in[3];
    const float* gamma = (const float*)d_in[4];
    float* out = (float*)d_out;

    // ws: qtr bf16 [B*N*8] (1MB) | ktr bf16 [B*N*16] (2MB) | v bf16 [B*C*N] (8MB)
    ushort* qtr = (ushort*)d_ws;
    ushort* ktr = qtr + (size_t)BATCH * NN * 8;
    ushort* vws = ktr + (size_t)BATCH * NN * 16;

    proj_kernel<<<dim3((BATCH * NN) / 64), dim3(256), 0, stream>>>(x, Wq, Wk, Wv, qtr, ktr, vws);
    attn_kernel<<<dim3((BATCH * NN) / 128), dim3(256), 0, stream>>>(qtr, ktr, vws, x, gamma, out);
}

// Round 8
// 142.366 us; speedup vs baseline: 11.0620x; 1.0138x over previous
//
#include <hip/hip_runtime.h>
#include <hip/hip_bf16.h>

#define BATCH 16
#define CC    64
#define NN    4096
#define MIDD  8

typedef __attribute__((ext_vector_type(8)))  short short8;
typedef __attribute__((ext_vector_type(16))) float f32x16;
typedef __attribute__((ext_vector_type(2)))  int   v2i;

static __device__ __forceinline__ ushort f2bf(float f) {
    return __bfloat16_as_ushort(__float2bfloat16(f));   // RNE
}

static __device__ __forceinline__ void glds16(const void* g, void* l) {
    __builtin_amdgcn_global_load_lds(
        (const __attribute__((address_space(1))) unsigned int*)g,
        (__attribute__((address_space(3))) unsigned int*)l, 16, 0, 0);
}

static __device__ __forceinline__ unsigned cvt_pk(float lo, float hi) {
    unsigned r;
    asm("v_cvt_pk_bf16_f32 %0, %1, %2" : "=v"(r) : "v"(lo), "v"(hi));
    return r;
}

// ---------------- projection via MFMA (unchanged from R7) -------------------
__global__ __launch_bounds__(256) void proj_kernel(
    const float* __restrict__ x,
    const float* __restrict__ Wq,
    const float* __restrict__ Wk,
    const float* __restrict__ Wv,
    ushort* __restrict__ qtr,
    ushort* __restrict__ ktr,
    ushort* __restrict__ v)
{
    __shared__ unsigned xT[64 * 32];   // [n][dw phys], 8 KB

    int tid = threadIdx.x;
    int b   = blockIdx.x >> 6;
    int n0  = (blockIdx.x & 63) * 64;

    {
        int n  = tid & 63;
        int cp = tid >> 6;
        const float* xb = x + (size_t)b * CC * NN + n0 + n;
#pragma unroll
        for (int rep = 0; rep < 8; ++rep) {
            int c = cp * 2 + rep * 8;
            float a0 = xb[(size_t)c * NN];
            float a1 = xb[(size_t)(c + 1) * NN];
            int dwlog = cp + rep * 4;
            xT[n * 32 + (dwlog ^ (n & 31))] = cvt_pk(a0, a1);
        }
    }

    int wv   = tid >> 6;
    int lane = tid & 63;
    int hi   = lane >> 5;
    int r    = lane & 31;
    int s_   = wv & 1;
    bool hiT = wv >= 2;

    short8 wfa[4], wfb[4];
    if (!hiT) {
        const float* r0 = (r < 8)  ? (Wq + r * 64)
                        : (r < 16) ? (Wk + (r - 8) * 64)
                                   : (Wv + (r - 16) * 64);
        const float* r1 = Wv + (16 + r) * 64;
#pragma unroll
        for (int kc = 0; kc < 4; ++kc) {
            const float4* p0 = (const float4*)(r0 + kc * 16 + hi * 8);
            const float4* p1 = (const float4*)(r1 + kc * 16 + hi * 8);
            float4 a = p0[0], c4 = p0[1];
            float4 e = p1[0], g4 = p1[1];
            union { short8 s8; unsigned u[4]; } wa, wb;
            wa.u[0] = cvt_pk(a.x, a.y);  wa.u[1] = cvt_pk(a.z, a.w);
            wa.u[2] = cvt_pk(c4.x, c4.y); wa.u[3] = cvt_pk(c4.z, c4.w);
            wb.u[0] = cvt_pk(e.x, e.y);  wb.u[1] = cvt_pk(e.z, e.w);
            wb.u[2] = cvt_pk(g4.x, g4.y); wb.u[3] = cvt_pk(g4.z, g4.w);
            wfa[kc] = wa.s8; wfb[kc] = wb.s8;
        }
    } else {
        const float* r2 = Wv + (size_t)(r < 16 ? (48 + r) : 48) * 64;
        short8 z8 = {};
#pragma unroll
        for (int kc = 0; kc < 4; ++kc) {
            const float4* p2 = (const float4*)(r2 + kc * 16 + hi * 8);
            float4 a = p2[0], c4 = p2[1];
            union { short8 s8; unsigned u[4]; } wa;
            wa.u[0] = cvt_pk(a.x, a.y);  wa.u[1] = cvt_pk(a.z, a.w);
            wa.u[2] = cvt_pk(c4.x, c4.y); wa.u[3] = cvt_pk(c4.z, c4.w);
            wfa[kc] = (r < 16) ? wa.s8 : z8;
            wfb[kc] = z8;
        }
    }

    __syncthreads();

    short8 bf[4];
    int nr = s_ * 32 + r;
#pragma unroll
    for (int kc = 0; kc < 4; ++kc) {
        union { short8 s8; unsigned u[4]; } bu;
#pragma unroll
        for (int i = 0; i < 4; ++i) {
            int dwlog = kc * 8 + hi * 4 + i;
            bu.u[i] = xT[nr * 32 + (dwlog ^ r)];
        }
        bf[kc] = bu.s8;
    }

    int ng = n0 + s_ * 32 + r;
    size_t nb = (size_t)b * NN + ng;
    const float SCLQ = 0.35355339059327373f * 1.4426950408889634f;

    if (!hiT) {
        f32x16 acc = {};
#pragma unroll
        for (int kc = 0; kc < 4; ++kc)
            acc = __builtin_amdgcn_mfma_f32_32x32x16_bf16(wfa[kc], bf[kc], acc, 0, 0, 0);
        uint2 qd, kd, zd; zd.x = 0; zd.y = 0;
        qd.x = cvt_pk(acc[0] * SCLQ, acc[1] * SCLQ);
        qd.y = cvt_pk(acc[2] * SCLQ, acc[3] * SCLQ);
        kd.x = cvt_pk(acc[4], acc[5]);
        kd.y = cvt_pk(acc[6], acc[7]);
        *(uint2*)(qtr + nb * 8 + hi * 4) = qd;
        *(uint2*)(ktr + nb * 16 + hi * 4) = kd;
        *(uint2*)(ktr + nb * 16 + 8 + hi * 4) = zd;
#pragma unroll
        for (int reg = 8; reg < 16; ++reg) {
            int ch = (reg & 3) + 8 * ((reg >> 2) - 2) + 4 * hi;
            v[((size_t)b * CC + ch) * NN + ng] = f2bf(acc[reg]);
        }
        f32x16 ac1 = {};
#pragma unroll
        for (int kc = 0; kc < 4; ++kc)
            ac1 = __builtin_amdgcn_mfma_f32_32x32x16_bf16(wfb[kc], bf[kc], ac1, 0, 0, 0);
#pragma unroll
        for (int reg = 0; reg < 16; ++reg) {
            int ch = 16 + (reg & 3) + 8 * (reg >> 2) + 4 * hi;
            v[((size_t)b * CC + ch) * NN + ng] = f2bf(ac1[reg]);
        }
    } else {
        f32x16 acc = {};
#pragma unroll
        for (int kc = 0; kc < 4; ++kc)
            acc = __builtin_amdgcn_mfma_f32_32x32x16_bf16(wfa[kc], bf[kc], acc, 0, 0, 0);
#pragma unroll
        for (int reg = 0; reg < 8; ++reg) {
            int ch = 48 + (reg & 3) + 8 * (reg >> 2) + 4 * hi;
            v[((size_t)b * CC + ch) * NN + ng] = f2bf(acc[reg]);
        }
    }
}

// ---------------- fused flash attention: 8 waves, key-split -----------------
// 512 blocks x 8 waves. Wave (qs, h): q-subtile qs (32 q), key half h (2048
// keys, 32 iters of 64). Two independent triple-buffered LDS pipelines
// (one per half, 30 KB each). No max-shift softmax -> halves combine by
// plain summation through LDS at the end.
// V: granule o*8+(s^ (o&7)); K: [key][mh] granule L=2k+mh, phys=L^((L>>3)&7).
__global__ __launch_bounds__(512, 4) void attn_kernel(
    const ushort* __restrict__ qtr,
    const ushort* __restrict__ ktr,
    const ushort* __restrict__ v,
    const float*  __restrict__ x,
    const float*  __restrict__ gamma,
    float* __restrict__ out)
{
    __shared__ __align__(16) char lds[2 * 3 * 10240];   // 60 KB

    int bid = blockIdx.x;
    int wg  = (bid & 7) * 64 + (bid >> 3);   // bijective XCD swizzle (512%8==0)
    int b   = wg >> 5;
    int qt  = wg & 31;

    int tid  = threadIdx.x;
    int wv   = tid >> 6;
    int qs   = wv & 3;
    int h    = wv >> 2;
    int lane = tid & 63;
    int hi   = lane >> 5;
    int ql   = lane & 31;
    int q0   = qt * 128 + qs * 32;
    int gt   = tid & 255;                    // group-local thread id

    short8 qf = *(const short8*)(qtr + ((size_t)b * NN + q0 + ql) * 8);
    float  gm = gamma[0];
    short8 zero8 = {};
    if (hi) qf = zero8;                      // B-frag rows m=8..15 = zero pad
    asm volatile("s_waitcnt vmcnt(0)" ::: "memory");

    const ushort* kbh = ktr + (size_t)b * NN * 16 + (size_t)h * 2048 * 16;
    const ushort* vbh = v   + (size_t)b * CC * NN + h * 2048;

    // V staging: group thread stages phys granules gt and gt+256 (linear dest)
    int oA = gt >> 3, sA = (gt & 7) ^ (oA & 7);
    int oB = oA + 32,  sB = (gt & 7) ^ (oB & 7);
    const ushort* vsrcA = vbh + (size_t)oA * NN + sA * 8;
    const ushort* vsrcB = vbh + (size_t)oB * NN + sB * 8;
    // K staging (gt<128): phys granule gt -> logical l -> key, mh
    int lk = gt ^ ((gt >> 3) & 7);
    const ushort* ksrc0 = kbh + (size_t)(lk >> 1) * 16 + (lk & 1) * 8;

    char* base = lds + h * 30720;
    int vdA = gt * 16, vdB = (gt + 256) * 16, kd_ = 8192 + gt * 16;
    char* b0 = base;
    char* b1 = base + 10240;
    char* b2 = base + 20480;

    // K read offsets (swizzled, hoisted)
    int L0 = ql * 2 + hi;
    int L1 = (32 + ql) * 2 + hi;
    int k0off = 8192 + (L0 ^ ((L0 >> 3) & 7)) * 16;
    int k1off = 8192 + (L1 ^ ((L1 >> 3) & 7)) * 16;

    union { short8 s8; ushort us[8]; } onesu;
#pragma unroll
    for (int i = 0; i < 8; ++i) onesu.us[i] = 0x3F80;
    short8 ones = onesu.s8;

    f32x16 zf   = {};
    f32x16 acc0 = {};
    f32x16 acc1 = {};
    f32x16 accl = {};

    // prologue: stage tiles 0, 1
    glds16(vsrcA, b0 + vdA); glds16(vsrcB, b0 + vdB);
    if (gt < 128) glds16(ksrc0, b0 + kd_);
    glds16(vsrcA + 64, b1 + vdA); glds16(vsrcB + 64, b1 + vdB);
    if (gt < 128) glds16(ksrc0 + 64 * 16, b1 + kd_);

    for (int t = 0; t < 32; ++t) {
        int k2 = ((t + 2) & 31) * 64;        // wraps harmlessly on last 2 iters

        __builtin_amdgcn_s_barrier();        // all done reading b2's old tile
        glds16(vsrcA + k2, b2 + vdA);
        glds16(vsrcB + k2, b2 + vdB);
        if (gt < 128) {
            glds16(ksrc0 + (size_t)k2 * 16, b2 + kd_);
            asm volatile("s_waitcnt vmcnt(6)" ::: "memory");  // my tile-t done
        } else {
            asm volatile("s_waitcnt vmcnt(4)" ::: "memory");
        }
        __builtin_amdgcn_s_barrier();        // tile t visible from all waves
        __builtin_amdgcn_sched_barrier(0);

#pragma unroll
        for (int c = 0; c < 2; ++c) {
            short8 kf = *(const short8*)(b0 + (c ? k1off : k0off));
            f32x16 s = __builtin_amdgcn_mfma_f32_32x32x16_bf16(kf, qf, zf, 0, 0, 0);

            float p[16];
#pragma unroll
            for (int r = 0; r < 16; ++r) p[r] = __builtin_amdgcn_exp2f(s[r]);

            unsigned u[8];
#pragma unroll
            for (int i = 0; i < 8; ++i) u[i] = cvt_pk(p[2 * i], p[2 * i + 1]);

            v2i r02 = __builtin_amdgcn_permlane32_swap(u[0], u[2], false, false);
            v2i r13 = __builtin_amdgcn_permlane32_swap(u[1], u[3], false, false);
            v2i r46 = __builtin_amdgcn_permlane32_swap(u[4], u[6], false, false);
            v2i r57 = __builtin_amdgcn_permlane32_swap(u[5], u[7], false, false);
            union { short8 s8; int i4[4]; } P0, P1;
            P0.i4[0] = r02.x; P0.i4[1] = r13.x; P0.i4[2] = r02.y; P0.i4[3] = r13.y;
            P1.i4[0] = r46.x; P1.i4[1] = r57.x; P1.i4[2] = r46.y; P1.i4[3] = r57.y;

            // V^T A-frags (swizzled reads, conflict-free), loaded per chunk
            int g0 = (ql * 8 + ((c * 4 + hi) ^ (ql & 7))) * 16;
            int g1 = (ql * 8 + ((c * 4 + 2 + hi) ^ (ql & 7))) * 16;
            short8 vA0 = *(const short8*)(b0 + g0);
            short8 vB0 = *(const short8*)(b0 + g0 + 4096);
            short8 vA1 = *(const short8*)(b0 + g1);
            short8 vB1 = *(const short8*)(b0 + g1 + 4096);

            __builtin_amdgcn_s_setprio(1);
            acc0 = __builtin_amdgcn_mfma_f32_32x32x16_bf16(vA0, P0.s8, acc0, 0, 0, 0);
            acc1 = __builtin_amdgcn_mfma_f32_32x32x16_bf16(vB0, P0.s8, acc1, 0, 0, 0);
            accl = __builtin_amdgcn_mfma_f32_32x32x16_bf16(ones, P0.s8, accl, 0, 0, 0);
            acc0 = __builtin_amdgcn_mfma_f32_32x32x16_bf16(vA1, P1.s8, acc0, 0, 0, 0);
            acc1 = __builtin_amdgcn_mfma_f32_32x32x16_bf16(vB1, P1.s8, acc1, 0, 0, 0);
            accl = __builtin_amdgcn_mfma_f32_32x32x16_bf16(ones, P1.s8, accl, 0, 0, 0);
            __builtin_amdgcn_s_setprio(0);
        }

        char* tp = b0; b0 = b1; b1 = b2; b2 = tp;   // rotate 3-deep
    }

    // ---- combine the two key halves through LDS (plain sums, no max-shift)
    asm volatile("s_waitcnt vmcnt(0)" ::: "memory");  // drain dead prefetches
    __syncthreads();

    float* cl = (float*)lds;
    if (h == 1) {
#pragma unroll
        for (int r = 0; r < 16; ++r) {
            int ch = (r & 3) + 8 * (r >> 2) + 4 * hi;
            cl[(qs * 64 + ch) * 32 + ql]      = acc0[r];
            cl[(qs * 64 + 32 + ch) * 32 + ql] = acc1[r];
        }
        cl[8192 + qs * 32 + ql] = accl[0];
    }
    __syncthreads();
    if (h == 0) {
        float den = accl[0] + cl[8192 + qs * 32 + ql];
        float inv = gm / den;
#pragma unroll
        for (int r = 0; r < 16; ++r) {
            int ch = (r & 3) + 8 * (r >> 2) + 4 * hi;
            float n0 = acc0[r] + cl[(qs * 64 + ch) * 32 + ql];
            float n1 = acc1[r] + cl[(qs * 64 + 32 + ch) * 32 + ql];
            size_t i0 = ((size_t)(b * CC + ch)) * NN + q0 + ql;
            size_t i1 = i0 + (size_t)32 * NN;
            out[i0] = n0 * inv + x[i0];
            out[i1] = n1 * inv + x[i1];
        }
    }
}

extern "C" void kernel_launch(void* const* d_in, const int* in_sizes, int n_in,
                              void* d_out, int out_size, void* d_ws, size_t ws_size,
                              hipStream_t stream) {
    const float* x     = (const float*)d_in[0];
    const float* Wq    = (const float*)d_in[1];
    const float* Wk    = (const float*)d_in[2];
    const float* Wv    = (const float*)d_in[3];
    const float* gamma = (const float*)d_in[4];
    float* out = (float*)d_out;

    // ws: qtr bf16 [B*N*8] (1MB) | ktr bf16 [B*N*16] (2MB) | v bf16 [B*C*N] (8MB)
    ushort* qtr = (ushort*)d_ws;
    ushort* ktr = qtr + (size_t)BATCH * NN * 8;
    ushort* vws = ktr + (size_t)BATCH * NN * 16;

    proj_kernel<<<dim3((BATCH * NN) / 64), dim3(256), 0, stream>>>(x, Wq, Wk, Wv, qtr, ktr, vws);
    attn_kernel<<<dim3((BATCH * NN) / 128), dim3(512), 0, stream>>>(qtr, ktr, vws, x, gamma, out);
}

// Round 9
// 142.062 us; speedup vs baseline: 11.0857x; 1.0021x over previous
//
#include <hip/hip_runtime.h>
#include <hip/hip_bf16.h>

#define BATCH 16
#define CC    64
#define NN    4096
#define MIDD  8

typedef __attribute__((ext_vector_type(8)))  short short8;
typedef __attribute__((ext_vector_type(16))) float f32x16;
typedef __attribute__((ext_vector_type(2)))  int   v2i;

static __device__ __forceinline__ ushort f2bf(float f) {
    return __bfloat16_as_ushort(__float2bfloat16(f));   // RNE
}

static __device__ __forceinline__ void glds16(const void* g, void* l) {
    __builtin_amdgcn_global_load_lds(
        (const __attribute__((address_space(1))) unsigned int*)g,
        (__attribute__((address_space(3))) unsigned int*)l, 16, 0, 0);
}

static __device__ __forceinline__ unsigned cvt_pk(float lo, float hi) {
    unsigned r;
    asm("v_cvt_pk_bf16_f32 %0, %1, %2" : "=v"(r) : "v"(lo), "v"(hi));
    return r;
}

// ---------------- projection via MFMA ---------------------------------------
// 512 blocks x 256 thr; block = batch b (blk>>5), 128 cols (2 n-tiles of 64).
// W A-frags (the expensive 64-lane gather) hoisted ONCE per block.
__global__ __launch_bounds__(256) void proj_kernel(
    const float* __restrict__ x,
    const float* __restrict__ Wq,
    const float* __restrict__ Wk,
    const float* __restrict__ Wv,
    ushort* __restrict__ qtr,
    ushort* __restrict__ ktr,
    ushort* __restrict__ v)
{
    __shared__ unsigned xT[64 * 32];   // [n][dw phys], 8 KB

    int tid = threadIdx.x;
    int b   = blockIdx.x >> 5;
    int c0  = (blockIdx.x & 31) * 128;

    int wv   = tid >> 6;
    int lane = tid & 63;
    int hi   = lane >> 5;
    int r    = lane & 31;
    int s_   = wv & 1;
    bool hiT = wv >= 2;

    // ---- hoisted W A-frags (bf16)
    short8 wfa[4], wfb[4];
    if (!hiT) {
        const float* r0 = (r < 8)  ? (Wq + r * 64)
                        : (r < 16) ? (Wk + (r - 8) * 64)
                                   : (Wv + (r - 16) * 64);
        const float* r1 = Wv + (16 + r) * 64;
#pragma unroll
        for (int kc = 0; kc < 4; ++kc) {
            const float4* p0 = (const float4*)(r0 + kc * 16 + hi * 8);
            const float4* p1 = (const float4*)(r1 + kc * 16 + hi * 8);
            float4 a = p0[0], c4 = p0[1];
            float4 e = p1[0], g4 = p1[1];
            union { short8 s8; unsigned u[4]; } wa, wb;
            wa.u[0] = cvt_pk(a.x, a.y);  wa.u[1] = cvt_pk(a.z, a.w);
            wa.u[2] = cvt_pk(c4.x, c4.y); wa.u[3] = cvt_pk(c4.z, c4.w);
            wb.u[0] = cvt_pk(e.x, e.y);  wb.u[1] = cvt_pk(e.z, e.w);
            wb.u[2] = cvt_pk(g4.x, g4.y); wb.u[3] = cvt_pk(g4.z, g4.w);
            wfa[kc] = wa.s8; wfb[kc] = wb.s8;
        }
    } else {
        const float* r2 = Wv + (size_t)(r < 16 ? (48 + r) : 48) * 64;
        short8 z8 = {};
#pragma unroll
        for (int kc = 0; kc < 4; ++kc) {
            const float4* p2 = (const float4*)(r2 + kc * 16 + hi * 8);
            float4 a = p2[0], c4 = p2[1];
            union { short8 s8; unsigned u[4]; } wa;
            wa.u[0] = cvt_pk(a.x, a.y);  wa.u[1] = cvt_pk(a.z, a.w);
            wa.u[2] = cvt_pk(c4.x, c4.y); wa.u[3] = cvt_pk(c4.z, c4.w);
            wfa[kc] = (r < 16) ? wa.s8 : z8;
            wfb[kc] = z8;
        }
    }

    int ns = tid & 63;
    int cp = tid >> 6;
    const float SCLQ = 0.35355339059327373f * 1.4426950408889634f;

    for (int it = 0; it < 2; ++it) {
        int n0 = c0 + it * 64;
        __syncthreads();                         // prev iter's LDS reads done
        {
            const float* xb = x + (size_t)b * CC * NN + n0 + ns;
#pragma unroll
            for (int rep = 0; rep < 8; ++rep) {
                int c = cp * 2 + rep * 8;
                float a0 = xb[(size_t)c * NN];
                float a1 = xb[(size_t)(c + 1) * NN];
                int dwlog = cp + rep * 4;
                xT[ns * 32 + (dwlog ^ (ns & 31))] = cvt_pk(a0, a1);
            }
        }
        __syncthreads();

        short8 bf[4];
        int nr = s_ * 32 + r;
#pragma unroll
        for (int kc = 0; kc < 4; ++kc) {
            union { short8 s8; unsigned u[4]; } bu;
#pragma unroll
            for (int i = 0; i < 4; ++i) {
                int dwlog = kc * 8 + hi * 4 + i;
                bu.u[i] = xT[nr * 32 + (dwlog ^ r)];
            }
            bf[kc] = bu.s8;
        }

        int ng = n0 + s_ * 32 + r;
        size_t nb = (size_t)b * NN + ng;

        if (!hiT) {
            f32x16 acc = {};
#pragma unroll
            for (int kc = 0; kc < 4; ++kc)
                acc = __builtin_amdgcn_mfma_f32_32x32x16_bf16(wfa[kc], bf[kc], acc, 0, 0, 0);
            uint2 qd, kd, zd; zd.x = 0; zd.y = 0;
            qd.x = cvt_pk(acc[0] * SCLQ, acc[1] * SCLQ);
            qd.y = cvt_pk(acc[2] * SCLQ, acc[3] * SCLQ);
            kd.x = cvt_pk(acc[4], acc[5]);
            kd.y = cvt_pk(acc[6], acc[7]);
            *(uint2*)(qtr + nb * 8 + hi * 4) = qd;
            *(uint2*)(ktr + nb * 16 + hi * 4) = kd;
            *(uint2*)(ktr + nb * 16 + 8 + hi * 4) = zd;
#pragma unroll
            for (int reg = 8; reg < 16; ++reg) {
                int ch = (reg & 3) + 8 * ((reg >> 2) - 2) + 4 * hi;
                v[((size_t)b * CC + ch) * NN + ng] = f2bf(acc[reg]);
            }
            f32x16 ac1 = {};
#pragma unroll
            for (int kc = 0; kc < 4; ++kc)
                ac1 = __builtin_amdgcn_mfma_f32_32x32x16_bf16(wfb[kc], bf[kc], ac1, 0, 0, 0);
#pragma unroll
            for (int reg = 0; reg < 16; ++reg) {
                int ch = 16 + (reg & 3) + 8 * (reg >> 2) + 4 * hi;
                v[((size_t)b * CC + ch) * NN + ng] = f2bf(ac1[reg]);
            }
        } else {
            f32x16 acc = {};
#pragma unroll
            for (int kc = 0; kc < 4; ++kc)
                acc = __builtin_amdgcn_mfma_f32_32x32x16_bf16(wfa[kc], bf[kc], acc, 0, 0, 0);
#pragma unroll
            for (int reg = 0; reg < 8; ++reg) {
                int ch = 48 + (reg & 3) + 8 * (reg >> 2) + 4 * hi;
                v[((size_t)b * CC + ch) * NN + ng] = f2bf(acc[reg]);
            }
        }
    }
}

// ---------------- fused flash attention: 4 waves, key-split, 4 blocks/CU ----
// 1024 blocks x 256 thr. Block = 64 q; wave (qs,h): q-subtile qs (32 q),
// key half h (2048 keys, 32 iters of 64). Two double-buffered pipelines
// (10 KB/buffer), 40 KB LDS -> 4 independent blocks/CU (phase diversity).
// V: granule o*8+(s^(o&7)); K: [key][mh], granule L=2k+mh, phys=L^((L>>3)&7).
// glds16 linear dest; swizzle on global source + LDS reads; vmcnt(5) counted.
__global__ __launch_bounds__(256, 4) void attn_kernel(
    const ushort* __restrict__ qtr,
    const ushort* __restrict__ ktr,
    const ushort* __restrict__ v,
    const float*  __restrict__ x,
    const float*  __restrict__ gamma,
    float* __restrict__ out)
{
    __shared__ __align__(16) char lds[2 * 2 * 10240];   // 40 KB

    int bid = blockIdx.x;
    int wg  = (bid & 7) * 128 + (bid >> 3);   // bijective XCD swizzle (1024%8==0)
    int b   = wg >> 6;
    int qt  = wg & 63;

    int tid  = threadIdx.x;
    int h    = tid >> 7;                      // key half
    int gt   = tid & 127;                     // group-local thread id
    int qs   = (tid >> 6) & 1;                // q-subtile
    int lane = tid & 63;
    int hi   = lane >> 5;
    int ql   = lane & 31;
    int q0   = qt * 64 + qs * 32;

    short8 qf = *(const short8*)(qtr + ((size_t)b * NN + q0 + ql) * 8);
    float  gm = gamma[0];
    short8 zero8 = {};
    if (hi) qf = zero8;                       // B-frag rows m=8..15 = zero pad
    asm volatile("s_waitcnt vmcnt(0)" ::: "memory");

    const ushort* kbh = ktr + (size_t)b * NN * 16 + (size_t)h * 2048 * 16;
    const ushort* vbh = v   + (size_t)b * CC * NN + h * 2048;

    // V staging: thread stages phys granules gt + j*128 (j=0..3), linear dest
    const ushort* vsrc[4];
    int vd[4];
#pragma unroll
    for (int j = 0; j < 4; ++j) {
        int g  = gt + j * 128;
        int o  = g >> 3;
        int sl = (g & 7) ^ (o & 7);
        vsrc[j] = vbh + (size_t)o * NN + sl * 8;
        vd[j]   = g * 16;
    }
    // K staging: phys granule gt -> logical -> (key, mh)
    int lk = gt ^ ((gt >> 3) & 7);
    const ushort* ksrc = kbh + (size_t)(lk >> 1) * 16 + (lk & 1) * 8;
    int kd = 8192 + gt * 16;

    char* base = lds + h * 20480;
    char* cur  = base;
    char* nxt  = base + 10240;

    // K read offsets (swizzled, hoisted)
    int L0 = ql * 2 + hi;
    int L1 = (32 + ql) * 2 + hi;
    int k0off = 8192 + (L0 ^ ((L0 >> 3) & 7)) * 16;
    int k1off = 8192 + (L1 ^ ((L1 >> 3) & 7)) * 16;

    union { short8 s8; ushort us[8]; } onesu;
#pragma unroll
    for (int i = 0; i < 8; ++i) onesu.us[i] = 0x3F80;
    short8 ones = onesu.s8;

    f32x16 zf   = {};
    f32x16 acc0 = {};
    f32x16 acc1 = {};
    f32x16 accl = {};

    // prologue: stage tile 0
#pragma unroll
    for (int j = 0; j < 4; ++j) glds16(vsrc[j], cur + vd[j]);
    glds16(ksrc, cur + kd);

    for (int t = 0; t < 32; ++t) {
        int k1 = ((t + 1) & 31) * 64;        // wraps harmlessly on last iter

        __builtin_amdgcn_s_barrier();        // all done reading nxt's old tile
#pragma unroll
        for (int j = 0; j < 4; ++j) glds16(vsrc[j] + k1, nxt + vd[j]);
        glds16(ksrc + (size_t)k1 * 16, nxt + kd);
        asm volatile("s_waitcnt vmcnt(5)" ::: "memory");  // tile-t loads landed
        __builtin_amdgcn_s_barrier();        // tile t visible from all waves
        __builtin_amdgcn_sched_barrier(0);

#pragma unroll
        for (int c = 0; c < 2; ++c) {
            short8 kf = *(const short8*)(cur + (c ? k1off : k0off));
            f32x16 s = __builtin_amdgcn_mfma_f32_32x32x16_bf16(kf, qf, zf, 0, 0, 0);

            float p[16];
#pragma unroll
            for (int r = 0; r < 16; ++r) p[r] = __builtin_amdgcn_exp2f(s[r]);

            unsigned u[8];
#pragma unroll
            for (int i = 0; i < 8; ++i) u[i] = cvt_pk(p[2 * i], p[2 * i + 1]);

            v2i r02 = __builtin_amdgcn_permlane32_swap(u[0], u[2], false, false);
            v2i r13 = __builtin_amdgcn_permlane32_swap(u[1], u[3], false, false);
            v2i r46 = __builtin_amdgcn_permlane32_swap(u[4], u[6], false, false);
            v2i r57 = __builtin_amdgcn_permlane32_swap(u[5], u[7], false, false);
            union { short8 s8; int i4[4]; } P0, P1;
            P0.i4[0] = r02.x; P0.i4[1] = r13.x; P0.i4[2] = r02.y; P0.i4[3] = r13.y;
            P1.i4[0] = r46.x; P1.i4[1] = r57.x; P1.i4[2] = r46.y; P1.i4[3] = r57.y;

            int g0 = (ql * 8 + ((c * 4 + hi) ^ (ql & 7))) * 16;
            int g1 = (ql * 8 + ((c * 4 + 2 + hi) ^ (ql & 7))) * 16;
            short8 vA0 = *(const short8*)(cur + g0);
            short8 vB0 = *(const short8*)(cur + g0 + 4096);
            short8 vA1 = *(const short8*)(cur + g1);
            short8 vB1 = *(const short8*)(cur + g1 + 4096);

            __builtin_amdgcn_s_setprio(1);
            acc0 = __builtin_amdgcn_mfma_f32_32x32x16_bf16(vA0, P0.s8, acc0, 0, 0, 0);
            acc1 = __builtin_amdgcn_mfma_f32_32x32x16_bf16(vB0, P0.s8, acc1, 0, 0, 0);
            accl = __builtin_amdgcn_mfma_f32_32x32x16_bf16(ones, P0.s8, accl, 0, 0, 0);
            acc0 = __builtin_amdgcn_mfma_f32_32x32x16_bf16(vA1, P1.s8, acc0, 0, 0, 0);
            acc1 = __builtin_amdgcn_mfma_f32_32x32x16_bf16(vB1, P1.s8, acc1, 0, 0, 0);
            accl = __builtin_amdgcn_mfma_f32_32x32x16_bf16(ones, P1.s8, accl, 0, 0, 0);
            __builtin_amdgcn_s_setprio(0);
        }

        char* tp = cur; cur = nxt; nxt = tp;
    }

    // ---- combine the two key halves through LDS (plain sums, no max-shift)
    asm volatile("s_waitcnt vmcnt(0)" ::: "memory");  // drain stray prefetches
    __syncthreads();

    float* cl = (float*)lds;
    if (h == 1) {
#pragma unroll
        for (int r = 0; r < 16; ++r) {
            int ch = (r & 3) + 8 * (r >> 2) + 4 * hi;
            cl[(qs * 64 + ch) * 32 + ql]      = acc0[r];
            cl[(qs * 64 + 32 + ch) * 32 + ql] = acc1[r];
        }
        cl[4096 + qs * 32 + ql] = accl[0];
    }
    __syncthreads();
    if (h == 0) {
        float den = accl[0] + cl[4096 + qs * 32 + ql];
        float inv = gm / den;
#pragma unroll
        for (int r = 0; r < 16; ++r) {
            int ch = (r & 3) + 8 * (r >> 2) + 4 * hi;
            float n0 = acc0[r] + cl[(qs * 64 + ch) * 32 + ql];
            float n1 = acc1[r] + cl[(qs * 64 + 32 + ch) * 32 + ql];
            size_t i0 = ((size_t)(b * CC + ch)) * NN + q0 + ql;
            size_t i1 = i0 + (size_t)32 * NN;
            out[i0] = n0 * inv + x[i0];
            out[i1] = n1 * inv + x[i1];
        }
    }
}

extern "C" void kernel_launch(void* const* d_in, const int* in_sizes, int n_in,
                              void* d_out, int out_size, void* d_ws, size_t ws_size,
                              hipStream_t stream) {
    const float* x     = (const float*)d_in[0];
    const float* Wq    = (const float*)d_in[1];
    const float* Wk    = (const float*)d_in[2];
    const float* Wv    = (const float*)d_in[3];
    const float* gamma = (const float*)d_in[4];
    float* out = (float*)d_out;

    // ws: qtr bf16 [B*N*8] (1MB) | ktr bf16 [B*N*16] (2MB) | v bf16 [B*C*N] (8MB)
    ushort* qtr = (ushort*)d_ws;
    ushort* ktr = qtr + (size_t)BATCH * NN * 8;
    ushort* vws = ktr + (size_t)BATCH * NN * 16;

    proj_kernel<<<dim3(BATCH * 32), dim3(256), 0, stream>>>(x, Wq, Wk, Wv, qtr, ktr, vws);
    attn_kernel<<<dim3(BATCH * 64), dim3(256), 0, stream>>>(qtr, ktr, vws, x, gamma, out);
}